// Round 2
// baseline (229.255 us; speedup 1.0000x reference)
//
#include <hip/hip_runtime.h>
#include <hip/hip_bf16.h>

typedef __attribute__((ext_vector_type(4))) float f32x4;
typedef __attribute__((ext_vector_type(8))) __bf16 bf16x8;
typedef __attribute__((ext_vector_type(4))) __bf16 bf16x4;

#define N_SEQ 128
#define L_RES 256
#define D_MSA 256
#define H_N 8
#define DH_N 32
#define DP_N 128
#define MROWS 32768
#define LDT 88  // LDS row stride (bf16 elems): 176B rows -> 16B aligned, 2-way-max bank conflicts

// ---------------- LayerNorm -> bf16 ----------------
__global__ __launch_bounds__(256) void ln_kernel(
    const float* __restrict__ msa, const float* __restrict__ g,
    const float* __restrict__ b, __bf16* __restrict__ xn)
{
  const int row = blockIdx.x * 4 + (threadIdx.x >> 6);
  const int lane = threadIdx.x & 63;
  const float* src = msa + (size_t)row * D_MSA + lane * 4;
  f32x4 x = *(const f32x4*)src;
  float s = x[0] + x[1] + x[2] + x[3];
  float s2 = x[0]*x[0] + x[1]*x[1] + x[2]*x[2] + x[3]*x[3];
#pragma unroll
  for (int d = 32; d >= 1; d >>= 1) {
    s  += __shfl_xor(s, d);
    s2 += __shfl_xor(s2, d);
  }
  const float mu  = s * (1.f / 256.f);
  const float inv = rsqrtf(s2 * (1.f / 256.f) - mu * mu + 1e-5f);
  const f32x4 gv = *(const f32x4*)(g + lane * 4);
  const f32x4 bv = *(const f32x4*)(b + lane * 4);
  bf16x4 o;
#pragma unroll
  for (int j = 0; j < 4; ++j) o[j] = (__bf16)((x[j] - mu) * inv * gv[j] + bv[j]);
  *(bf16x4*)(xn + (size_t)row * D_MSA + lane * 4) = o;
}

// ---------------- pair bias projection: bias[h][i][j] = pair[i][j][:] @ Wb[:,h] + bb[h] ----------------
__global__ __launch_bounds__(256) void bias_kernel(
    const float* __restrict__ pair, const float* __restrict__ Wb,
    const float* __restrict__ bb, float* __restrict__ biasf)
{
  __shared__ float wbs[1024];
  const int t = threadIdx.x;
#pragma unroll
  for (int r2 = 0; r2 < 4; ++r2) wbs[t + 256 * r2] = Wb[t + 256 * r2];
  __syncthreads();
  const int i = blockIdx.x, j = t;
  const float* src = pair + ((size_t)i * 256 + j) * 128;
  float acc[8];
#pragma unroll
  for (int hh = 0; hh < 8; ++hh) acc[hh] = bb[hh];
  for (int p = 0; p < 128; p += 4) {
    const f32x4 pv = *(const f32x4*)(src + p);
#pragma unroll
    for (int q2 = 0; q2 < 4; ++q2)
#pragma unroll
      for (int hh = 0; hh < 8; ++hh) acc[hh] += pv[q2] * wbs[(p + q2) * 8 + hh];
  }
#pragma unroll
  for (int hh = 0; hh < 8; ++hh) biasf[((size_t)hh * 256 + i) * 256 + j] = acc[hh];
}

// ---------------- weight prep: Wt[w][n][k] = W_w[k][n] in bf16, w in {q,k,v,g,o} ----------------
__global__ __launch_bounds__(256) void prep_kernel(
    const float* __restrict__ Wq, const float* __restrict__ Wk,
    const float* __restrict__ Wv, const float* __restrict__ Wg,
    const float* __restrict__ Wo, __bf16* __restrict__ Wt)
{
  const int w = blockIdx.x >> 8, n2 = blockIdx.x & 255, k = threadIdx.x;
  const float* W = (w == 0) ? Wq : (w == 1) ? Wk : (w == 2) ? Wv : (w == 3) ? Wg : Wo;
  Wt[((size_t)w * 256 + n2) * 256 + k] = (__bf16)W[(size_t)k * 256 + n2];
}

// ---------------- fused Q/K/V/Gate GEMM: [32768,256] @ [256,1024] ----------------
__global__ __launch_bounds__(256) void qkvg_gemm(
    const __bf16* __restrict__ xn, const __bf16* __restrict__ Wt,
    const float* __restrict__ bq, const float* __restrict__ bk,
    const float* __restrict__ bv, const float* __restrict__ bg,
    __bf16* __restrict__ qb, __bf16* __restrict__ kb,
    __bf16* __restrict__ vb, float* __restrict__ gate)
{
  __shared__ alignas(16) __bf16 Al[128 * LDT];
  __shared__ alignas(16) __bf16 Bl[128 * LDT];
  const int t = threadIdx.x;
  const int wave = t >> 6, lane = t & 63;
  const int l15 = lane & 15, l16 = lane >> 4;
  const int m0 = blockIdx.x * 128;
  const int bn = blockIdx.y;
  const int w = bn >> 1;
  const int nloc0 = (bn & 1) * 128;
  const __bf16* Wtw = Wt + (size_t)w * 65536;
  const int wm = (wave >> 1) * 64, wn = (wave & 1) * 64;

  f32x4 acc[4][4];
#pragma unroll
  for (int i = 0; i < 4; ++i)
#pragma unroll
    for (int j = 0; j < 4; ++j) acc[i][j] = (f32x4){0.f, 0.f, 0.f, 0.f};

  const int sr = t >> 1, sc = (t & 1) * 32;
  for (int kt = 0; kt < 4; ++kt) {
    const int k0 = kt * 64;
    const bf16x8* ga = (const bf16x8*)(xn  + (size_t)(m0 + sr) * 256 + k0 + sc);
    const bf16x8* gb = (const bf16x8*)(Wtw + (size_t)(nloc0 + sr) * 256 + k0 + sc);
    bf16x8* da = (bf16x8*)&Al[sr * LDT + sc];
    bf16x8* db = (bf16x8*)&Bl[sr * LDT + sc];
#pragma unroll
    for (int j = 0; j < 4; ++j) { da[j] = ga[j]; db[j] = gb[j]; }
    __syncthreads();
#pragma unroll
    for (int kk = 0; kk < 2; ++kk) {
      bf16x8 a[4], bfr[4];
#pragma unroll
      for (int mi = 0; mi < 4; ++mi)
        a[mi] = *(const bf16x8*)&Al[(wm + mi * 16 + l15) * LDT + kk * 32 + l16 * 8];
#pragma unroll
      for (int ni = 0; ni < 4; ++ni)
        bfr[ni] = *(const bf16x8*)&Bl[(wn + ni * 16 + l15) * LDT + kk * 32 + l16 * 8];
#pragma unroll
      for (int mi = 0; mi < 4; ++mi)
#pragma unroll
        for (int ni = 0; ni < 4; ++ni)
          acc[mi][ni] = __builtin_amdgcn_mfma_f32_16x16x32_bf16(a[mi], bfr[ni], acc[mi][ni], 0, 0, 0);
    }
    __syncthreads();
  }
#pragma unroll
  for (int mi = 0; mi < 4; ++mi)
#pragma unroll
    for (int ni = 0; ni < 4; ++ni)
#pragma unroll
      for (int r = 0; r < 4; ++r) {
        const int grow = m0 + wm + mi * 16 + l16 * 4 + r;
        const int gcol = nloc0 + wn + ni * 16 + l15;
        const float v = acc[mi][ni][r];
        const int n = grow >> 8, i2 = grow & 255, h = gcol >> 5, dh = gcol & 31;
        const size_t hoff = (((size_t)n * 8 + h) * 256 + i2) * 32 + dh;
        if (w == 0)      qb[hoff] = (__bf16)((v + bq[gcol]) * 0.1767766952966369f); // 1/sqrt(32) folded in
        else if (w == 1) kb[hoff] = (__bf16)(v + bk[gcol]);
        else if (w == 2) vb[hoff] = (__bf16)(v + bv[gcol]);
        else gate[(size_t)grow * 256 + gcol] = 1.f / (1.f + __expf(-(v + bg[gcol])));
      }
}

// ---------------- flash attention per (n,h): block = 4 waves x 64 q-rows ----------------
__global__ __launch_bounds__(256) void attn_kernel(
    const __bf16* __restrict__ qb, const __bf16* __restrict__ kb,
    const __bf16* __restrict__ vb, const float* __restrict__ biasf,
    const int* __restrict__ mask, __bf16* __restrict__ opre)
{
  __shared__ alignas(16) __bf16 Kl[256 * 40];   // [key][dh], stride 40 -> 80B rows
  __shared__ alignas(16) __bf16 Vt[32 * 264];   // [dh][key], stride 264 -> 528B rows
  __shared__ alignas(16) __bf16 Pl[4 * 64 * 40];
  const int t = threadIdx.x, wave = t >> 6, lane = t & 63;
  const int l15 = lane & 15, l16 = lane >> 4;
  const int nh = blockIdx.x;
  const int n = nh >> 3, h = nh & 7;

  {
    const bf16x8* ks = (const bf16x8*)(kb + (size_t)nh * 8192 + t * 32);
    bf16x8* kd = (bf16x8*)&Kl[t * 40];
#pragma unroll
    for (int j = 0; j < 4; ++j) kd[j] = ks[j];
    const bf16x8* vs = (const bf16x8*)(vb + (size_t)nh * 8192 + t * 32);
    bf16x8 vv[4];
#pragma unroll
    for (int j = 0; j < 4; ++j) vv[j] = vs[j];
#pragma unroll
    for (int j = 0; j < 4; ++j)
#pragma unroll
      for (int e = 0; e < 8; ++e) Vt[(j * 8 + e) * 264 + t] = vv[j][e];
  }
  __syncthreads();

  const int qrow0 = wave * 64;
  bf16x8 qf[4];
#pragma unroll
  for (int mi = 0; mi < 4; ++mi)
    qf[mi] = *(const bf16x8*)(qb + ((size_t)nh * 256 + qrow0 + mi * 16 + l15) * 32 + l16 * 8);

  const f32x4 zero4 = {0.f, 0.f, 0.f, 0.f};
  f32x4 oacc[4][2];
  float mrun[16], lrun[16];
#pragma unroll
  for (int i = 0; i < 16; ++i) { mrun[i] = -1e30f; lrun[i] = 0.f; }
#pragma unroll
  for (int mi = 0; mi < 4; ++mi)
#pragma unroll
    for (int nc = 0; nc < 2; ++nc) oacc[mi][nc] = zero4;

  const float* biash = biasf + (size_t)h * 65536;
  const int* maskn = mask + n * 256;
  __bf16* Pw = &Pl[wave * 64 * 40];

  for (int j0 = 0; j0 < 256; j0 += 32) {
    f32x4 s[2][4];
#pragma unroll
    for (int jt = 0; jt < 2; ++jt) {
      const int j16 = j0 + jt * 16;
      const bf16x8 kf = *(const bf16x8*)&Kl[(j16 + l15) * 40 + l16 * 8];
      const int mv = maskn[j16 + l15];
#pragma unroll
      for (int mi = 0; mi < 4; ++mi) {
        f32x4 sv = __builtin_amdgcn_mfma_f32_16x16x32_bf16(qf[mi], kf, zero4, 0, 0, 0);
#pragma unroll
        for (int r = 0; r < 4; ++r) {
          const float x = sv[r] + biash[(size_t)(qrow0 + mi * 16 + l16 * 4 + r) * 256 + j16 + l15];
          sv[r] = mv ? x : -1e9f;
        }
        s[jt][mi] = sv;
      }
    }
#pragma unroll
    for (int mi = 0; mi < 4; ++mi) {
      f32x4 mx;
#pragma unroll
      for (int r = 0; r < 4; ++r) mx[r] = fmaxf(s[0][mi][r], s[1][mi][r]);
#pragma unroll
      for (int d2 = 1; d2 < 16; d2 <<= 1)
#pragma unroll
        for (int r = 0; r < 4; ++r) mx[r] = fmaxf(mx[r], __shfl_xor(mx[r], d2));
#pragma unroll
      for (int r = 0; r < 4; ++r) {
        const int sidx = mi * 4 + r;
        const float mnew = fmaxf(mrun[sidx], mx[r]);
        const float alpha = __expf(mrun[sidx] - mnew);
        mrun[sidx] = mnew;
        const float p0 = __expf(s[0][mi][r] - mnew);
        const float p1 = __expf(s[1][mi][r] - mnew);
        float ps = p0 + p1;
#pragma unroll
        for (int d2 = 1; d2 < 16; d2 <<= 1) ps += __shfl_xor(ps, d2);
        lrun[sidx] = lrun[sidx] * alpha + ps;
        oacc[mi][0][r] *= alpha;
        oacc[mi][1][r] *= alpha;
        const int prow = mi * 16 + l16 * 4 + r;
        Pw[prow * 40 + l15]      = (__bf16)p0;
        Pw[prow * 40 + 16 + l15] = (__bf16)p1;
      }
    }
    __syncthreads();
#pragma unroll
    for (int mi = 0; mi < 4; ++mi) {
      const bf16x8 pa = *(const bf16x8*)&Pw[(mi * 16 + l15) * 40 + l16 * 8];
#pragma unroll
      for (int nc = 0; nc < 2; ++nc) {
        const bf16x8 vf = *(const bf16x8*)&Vt[(nc * 16 + l15) * 264 + j0 + l16 * 8];
        oacc[mi][nc] = __builtin_amdgcn_mfma_f32_16x16x32_bf16(pa, vf, oacc[mi][nc], 0, 0, 0);
      }
    }
    __syncthreads();
  }
#pragma unroll
  for (int mi = 0; mi < 4; ++mi)
#pragma unroll
    for (int r = 0; r < 4; ++r) {
      const float invl = 1.f / lrun[mi * 4 + r];
      const int qr = qrow0 + mi * 16 + l16 * 4 + r;
#pragma unroll
      for (int nc = 0; nc < 2; ++nc)
        opre[((size_t)n * 256 + qr) * 256 + h * 32 + nc * 16 + l15] =
            (__bf16)(oacc[mi][nc][r] * invl);
    }
}

// ---------------- output projection + gate ----------------
__global__ __launch_bounds__(256) void wo_gemm(
    const __bf16* __restrict__ A, const __bf16* __restrict__ Wtw,
    const float* __restrict__ bo, const float* __restrict__ gate,
    float* __restrict__ out)
{
  __shared__ alignas(16) __bf16 Al[128 * LDT];
  __shared__ alignas(16) __bf16 Bl[128 * LDT];
  const int t = threadIdx.x;
  const int wave = t >> 6, lane = t & 63;
  const int l15 = lane & 15, l16 = lane >> 4;
  const int m0 = blockIdx.x * 128;
  const int nloc0 = blockIdx.y * 128;
  const int wm = (wave >> 1) * 64, wn = (wave & 1) * 64;

  f32x4 acc[4][4];
#pragma unroll
  for (int i = 0; i < 4; ++i)
#pragma unroll
    for (int j = 0; j < 4; ++j) acc[i][j] = (f32x4){0.f, 0.f, 0.f, 0.f};

  const int sr = t >> 1, sc = (t & 1) * 32;
  for (int kt = 0; kt < 4; ++kt) {
    const int k0 = kt * 64;
    const bf16x8* ga = (const bf16x8*)(A   + (size_t)(m0 + sr) * 256 + k0 + sc);
    const bf16x8* gb = (const bf16x8*)(Wtw + (size_t)(nloc0 + sr) * 256 + k0 + sc);
    bf16x8* da = (bf16x8*)&Al[sr * LDT + sc];
    bf16x8* db = (bf16x8*)&Bl[sr * LDT + sc];
#pragma unroll
    for (int j = 0; j < 4; ++j) { da[j] = ga[j]; db[j] = gb[j]; }
    __syncthreads();
#pragma unroll
    for (int kk = 0; kk < 2; ++kk) {
      bf16x8 a[4], bfr[4];
#pragma unroll
      for (int mi = 0; mi < 4; ++mi)
        a[mi] = *(const bf16x8*)&Al[(wm + mi * 16 + l15) * LDT + kk * 32 + l16 * 8];
#pragma unroll
      for (int ni = 0; ni < 4; ++ni)
        bfr[ni] = *(const bf16x8*)&Bl[(wn + ni * 16 + l15) * LDT + kk * 32 + l16 * 8];
#pragma unroll
      for (int mi = 0; mi < 4; ++mi)
#pragma unroll
        for (int ni = 0; ni < 4; ++ni)
          acc[mi][ni] = __builtin_amdgcn_mfma_f32_16x16x32_bf16(a[mi], bfr[ni], acc[mi][ni], 0, 0, 0);
    }
    __syncthreads();
  }
#pragma unroll
  for (int mi = 0; mi < 4; ++mi)
#pragma unroll
    for (int ni = 0; ni < 4; ++ni)
#pragma unroll
      for (int r = 0; r < 4; ++r) {
        const int grow = m0 + wm + mi * 16 + l16 * 4 + r;
        const int gcol = nloc0 + wn + ni * 16 + l15;
        const size_t o = (size_t)grow * 256 + gcol;
        out[o] = (acc[mi][ni][r] + bo[gcol]) * gate[o];
      }
}

extern "C" void kernel_launch(void* const* d_in, const int* in_sizes, int n_in,
                              void* d_out, int out_size, void* d_ws, size_t ws_size,
                              hipStream_t stream)
{
  const float* msa  = (const float*)d_in[0];
  const float* pair = (const float*)d_in[1];
  const int*   mask = (const int*)d_in[2];
  const float* ln_g = (const float*)d_in[3];
  const float* ln_b = (const float*)d_in[4];
  const float* Wq = (const float*)d_in[5];  const float* bq = (const float*)d_in[6];
  const float* Wk = (const float*)d_in[7];  const float* bk = (const float*)d_in[8];
  const float* Wv = (const float*)d_in[9];  const float* bv = (const float*)d_in[10];
  const float* Wb = (const float*)d_in[11]; const float* bb = (const float*)d_in[12];
  const float* Wo = (const float*)d_in[13]; const float* bo = (const float*)d_in[14];
  const float* Wg = (const float*)d_in[15]; const float* bg = (const float*)d_in[16];
  float* out = (float*)d_out;

  char* ws = (char*)d_ws;
  __bf16* xn   = (__bf16*)(ws);
  __bf16* qb   = (__bf16*)(ws + 16777216);
  __bf16* kb   = (__bf16*)(ws + 2 * 16777216);
  __bf16* vb   = (__bf16*)(ws + 3 * 16777216);
  __bf16* opre = (__bf16*)(ws + 4 * 16777216);
  __bf16* Wt   = (__bf16*)(ws + 5 * 16777216);          // 5*65536 bf16 = 640KB
  float*  gate = (float*)(ws + 5 * 16777216 + 655360);  // 33.5MB
  float*  biasf= (float*)(ws + 5 * 16777216 + 655360 + 33554432); // 2MB

  hipLaunchKernelGGL(ln_kernel,   dim3(8192),    dim3(256), 0, stream, msa, ln_g, ln_b, xn);
  hipLaunchKernelGGL(bias_kernel, dim3(256),     dim3(256), 0, stream, pair, Wb, bb, biasf);
  hipLaunchKernelGGL(prep_kernel, dim3(1280),    dim3(256), 0, stream, Wq, Wk, Wv, Wg, Wo, Wt);
  hipLaunchKernelGGL(qkvg_gemm,   dim3(256, 8),  dim3(256), 0, stream, xn, Wt, bq, bk, bv, bg, qb, kb, vb, gate);
  hipLaunchKernelGGL(attn_kernel, dim3(1024),    dim3(256), 0, stream, qb, kb, vb, biasf, mask, opre);
  hipLaunchKernelGGL(wo_gemm,     dim3(256, 2),  dim3(256), 0, stream, opre, Wt + 4 * 65536, bo, gate, out);
}

// Round 3
// 194.508 us; speedup vs baseline: 1.1786x; 1.1786x over previous
//
#include <hip/hip_runtime.h>
#include <hip/hip_bf16.h>

typedef __attribute__((ext_vector_type(4))) float f32x4;
typedef __attribute__((ext_vector_type(16))) float f32x16;
typedef __attribute__((ext_vector_type(8))) __bf16 bf16x8;
typedef __attribute__((ext_vector_type(4))) __bf16 bf16x4;
typedef __attribute__((ext_vector_type(2))) __bf16 bf16x2;
typedef __attribute__((ext_vector_type(4))) unsigned u32x4;

#define N_SEQ 128
#define L_RES 256
#define D_MSA 256
#define H_N 8
#define DH_N 32
#define LDT 88   // GEMM LDS stride
#define VTS 264  // attn V^T LDS stride (528B rows, 16B-aligned)
#define L2E 1.4426950408889634f

// ---------------- LayerNorm -> bf16 ----------------
__global__ __launch_bounds__(256) void ln_kernel(
    const float* __restrict__ msa, const float* __restrict__ g,
    const float* __restrict__ b, __bf16* __restrict__ xn)
{
  const int row = blockIdx.x * 4 + (threadIdx.x >> 6);
  const int lane = threadIdx.x & 63;
  const float* src = msa + (size_t)row * D_MSA + lane * 4;
  f32x4 x = *(const f32x4*)src;
  float s = x[0] + x[1] + x[2] + x[3];
  float s2 = x[0]*x[0] + x[1]*x[1] + x[2]*x[2] + x[3]*x[3];
#pragma unroll
  for (int d = 32; d >= 1; d >>= 1) {
    s  += __shfl_xor(s, d);
    s2 += __shfl_xor(s2, d);
  }
  const float mu  = s * (1.f / 256.f);
  const float inv = rsqrtf(s2 * (1.f / 256.f) - mu * mu + 1e-5f);
  const f32x4 gv = *(const f32x4*)(g + lane * 4);
  const f32x4 bv = *(const f32x4*)(b + lane * 4);
  bf16x4 o;
#pragma unroll
  for (int j = 0; j < 4; ++j) o[j] = (__bf16)((x[j] - mu) * inv * gv[j] + bv[j]);
  *(bf16x4*)(xn + (size_t)row * D_MSA + lane * 4) = o;
}

// ---- pair bias projection -> packed layout biasP[h][k>>2][q][k&3] (f32) ----
__global__ __launch_bounds__(256) void bias_kernel(
    const float* __restrict__ pair, const float* __restrict__ Wb,
    const float* __restrict__ bb, float* __restrict__ biasP)
{
  __shared__ float wbs[1024];
  const int t = threadIdx.x;
#pragma unroll
  for (int r2 = 0; r2 < 4; ++r2) wbs[t + 256 * r2] = Wb[t + 256 * r2];
  __syncthreads();
  const int i = blockIdx.x, j = t;   // i = query row, j = key
  const float* src = pair + ((size_t)i * 256 + j) * 128;
  float acc[8];
#pragma unroll
  for (int hh = 0; hh < 8; ++hh) acc[hh] = bb[hh];
  for (int p = 0; p < 128; p += 4) {
    const f32x4 pv = *(const f32x4*)(src + p);
#pragma unroll
    for (int q2 = 0; q2 < 4; ++q2)
#pragma unroll
      for (int hh = 0; hh < 8; ++hh) acc[hh] += pv[q2] * wbs[(p + q2) * 8 + hh];
  }
#pragma unroll
  for (int hh = 0; hh < 8; ++hh)
    biasP[(size_t)hh * 65536 + (j >> 2) * 1024 + i * 4 + (j & 3)] = acc[hh];
}

// ---------------- weight prep: Wt[w][n][k] = W_w[k][n] in bf16 ----------------
__global__ __launch_bounds__(256) void prep_kernel(
    const float* __restrict__ Wq, const float* __restrict__ Wk,
    const float* __restrict__ Wv, const float* __restrict__ Wg,
    const float* __restrict__ Wo, __bf16* __restrict__ Wt)
{
  const int w = blockIdx.x >> 8, n2 = blockIdx.x & 255, k = threadIdx.x;
  const float* W = (w == 0) ? Wq : (w == 1) ? Wk : (w == 2) ? Wv : (w == 3) ? Wg : Wo;
  Wt[((size_t)w * 256 + n2) * 256 + k] = (__bf16)W[(size_t)k * 256 + n2];
}

// ---------------- mask -> additive float ----------------
__global__ __launch_bounds__(256) void maskprep_kernel(
    const int* __restrict__ mask, float* __restrict__ maskF)
{
  const int i = blockIdx.x * 256 + threadIdx.x;
  maskF[i] = mask[i] ? 0.f : -1e9f;
}

// ---------------- fused Q/K/V/Gate GEMM: [32768,256] @ [256,1024] ----------------
__global__ __launch_bounds__(256) void qkvg_gemm(
    const __bf16* __restrict__ xn, const __bf16* __restrict__ Wt,
    const float* __restrict__ bq, const float* __restrict__ bk,
    const float* __restrict__ bv, const float* __restrict__ bg,
    __bf16* __restrict__ qb, __bf16* __restrict__ kb,
    __bf16* __restrict__ vb, float* __restrict__ gate)
{
  __shared__ alignas(16) __bf16 Al[128 * LDT];
  __shared__ alignas(16) __bf16 Bl[128 * LDT];
  const int t = threadIdx.x;
  const int wave = t >> 6, lane = t & 63;
  const int l15 = lane & 15, l16 = lane >> 4;
  const int m0 = blockIdx.x * 128;
  const int bn = blockIdx.y;
  const int w = bn >> 1;
  const int nloc0 = (bn & 1) * 128;
  const __bf16* Wtw = Wt + (size_t)w * 65536;
  const int wm = (wave >> 1) * 64, wn = (wave & 1) * 64;

  f32x4 acc[4][4];
#pragma unroll
  for (int i = 0; i < 4; ++i)
#pragma unroll
    for (int j = 0; j < 4; ++j) acc[i][j] = (f32x4){0.f, 0.f, 0.f, 0.f};

  const int sr = t >> 1, sc = (t & 1) * 32;
  for (int kt = 0; kt < 4; ++kt) {
    const int k0 = kt * 64;
    const bf16x8* ga = (const bf16x8*)(xn  + (size_t)(m0 + sr) * 256 + k0 + sc);
    const bf16x8* gb = (const bf16x8*)(Wtw + (size_t)(nloc0 + sr) * 256 + k0 + sc);
    bf16x8* da = (bf16x8*)&Al[sr * LDT + sc];
    bf16x8* db = (bf16x8*)&Bl[sr * LDT + sc];
#pragma unroll
    for (int j = 0; j < 4; ++j) { da[j] = ga[j]; db[j] = gb[j]; }
    __syncthreads();
#pragma unroll
    for (int kk = 0; kk < 2; ++kk) {
      bf16x8 a[4], bfr[4];
#pragma unroll
      for (int mi = 0; mi < 4; ++mi)
        a[mi] = *(const bf16x8*)&Al[(wm + mi * 16 + l15) * LDT + kk * 32 + l16 * 8];
#pragma unroll
      for (int ni = 0; ni < 4; ++ni)
        bfr[ni] = *(const bf16x8*)&Bl[(wn + ni * 16 + l15) * LDT + kk * 32 + l16 * 8];
#pragma unroll
      for (int mi = 0; mi < 4; ++mi)
#pragma unroll
        for (int ni = 0; ni < 4; ++ni)
          acc[mi][ni] = __builtin_amdgcn_mfma_f32_16x16x32_bf16(a[mi], bfr[ni], acc[mi][ni], 0, 0, 0);
    }
    __syncthreads();
  }
#pragma unroll
  for (int mi = 0; mi < 4; ++mi)
#pragma unroll
    for (int ni = 0; ni < 4; ++ni)
#pragma unroll
      for (int r = 0; r < 4; ++r) {
        const int grow = m0 + wm + mi * 16 + l16 * 4 + r;
        const int gcol = nloc0 + wn + ni * 16 + l15;
        const float v = acc[mi][ni][r];
        const int n = grow >> 8, i2 = grow & 255, h = gcol >> 5, dh = gcol & 31;
        const size_t hoff = (((size_t)n * 8 + h) * 256 + i2) * 32 + dh;
        if (w == 0)      qb[hoff] = (__bf16)((v + bq[gcol]) * 0.1767766952966369f); // 1/sqrt(32)
        else if (w == 1) kb[hoff] = (__bf16)(v + bk[gcol]);
        else if (w == 2) vb[hoff] = (__bf16)(v + bv[gcol]);
        else gate[(size_t)grow * 256 + gcol] = 1.f / (1.f + __expf(-(v + bg[gcol])));
      }
}

// ---------------- flash attention v2: swapped 32x32 MFMA, in-register softmax ----------------
// Block = one (n,h); 4 waves x 64 queries (2 q-tiles of 32); KV in tiles of 32.
// S^T = mfma_32x32x16(K, Q): lane holds col q=lane&31, rows key=(r&3)+8*(r>>2)+4*hi.
__device__ __forceinline__ unsigned pk2(float a, float b) {
  bf16x2 t; t[0] = (__bf16)a; t[1] = (__bf16)b;
  return __builtin_bit_cast(unsigned, t);
}

__global__ __launch_bounds__(256, 4) void attn_kernel(
    const __bf16* __restrict__ qb, const __bf16* __restrict__ kb,
    const __bf16* __restrict__ vb, const float* __restrict__ biasP,
    const float* __restrict__ maskF, __bf16* __restrict__ opre)
{
  __shared__ alignas(16) __bf16 Vt[32 * VTS];   // V^T [dh][key]
  const int t = threadIdx.x, wave = t >> 6, lane = t & 63;
  const int l31 = lane & 31, hi = lane >> 5;
  const int nh = blockIdx.x, n = nh >> 3, h = nh & 7;
  const __bf16* kbh = kb + (size_t)nh * 8192;
  const __bf16* qbh = qb + (size_t)nh * 8192;

  { // stage V^T (one-time)
    const bf16x8* vs = (const bf16x8*)(vb + (size_t)nh * 8192 + t * 32);
    bf16x8 vv[4];
#pragma unroll
    for (int j = 0; j < 4; ++j) vv[j] = vs[j];
#pragma unroll
    for (int j = 0; j < 4; ++j)
#pragma unroll
      for (int e = 0; e < 8; ++e) Vt[(j * 8 + e) * VTS + t] = vv[j][e];
  }
  __syncthreads();

  const int q0 = wave * 64;
  bf16x8 Qf[2][2];
#pragma unroll
  for (int qt = 0; qt < 2; ++qt)
#pragma unroll
    for (int sl = 0; sl < 2; ++sl)
      Qf[qt][sl] = *(const bf16x8*)(qbh + (size_t)(q0 + qt * 32 + l31) * 32 + sl * 16 + hi * 8);

  f32x16 Ot[2];
#pragma unroll
  for (int r = 0; r < 16; ++r) { Ot[0][r] = 0.f; Ot[1][r] = 0.f; }
  float mrun[2] = {-1e30f, -1e30f}, lrun[2] = {0.f, 0.f};

  const float* bp = biasP + (size_t)h * 65536;
  const float* mf = maskF + n * 256;

#pragma unroll 2
  for (int k0 = 0; k0 < 256; k0 += 32) {
    const bf16x8 Kf0 = *(const bf16x8*)(kbh + (size_t)(k0 + l31) * 32 + hi * 8);
    const bf16x8 Kf1 = *(const bf16x8*)(kbh + (size_t)(k0 + l31) * 32 + 16 + hi * 8);
    const bf16x8 Vf0 = *(const bf16x8*)&Vt[l31 * VTS + k0 + hi * 8];
    const bf16x8 Vf1 = *(const bf16x8*)&Vt[l31 * VTS + k0 + 16 + hi * 8];
    f32x4 mk[4];
#pragma unroll
    for (int g = 0; g < 4; ++g) mk[g] = *(const f32x4*)(mf + k0 + 8 * g + 4 * hi);

#pragma unroll
    for (int qt = 0; qt < 2; ++qt) {
      f32x16 st;
#pragma unroll
      for (int r = 0; r < 16; ++r) st[r] = 0.f;
      st = __builtin_amdgcn_mfma_f32_32x32x16_bf16(Kf0, Qf[qt][0], st, 0, 0, 0);
      st = __builtin_amdgcn_mfma_f32_32x32x16_bf16(Kf1, Qf[qt][1], st, 0, 0, 0);
      const int q = q0 + qt * 32 + l31;
#pragma unroll
      for (int g = 0; g < 4; ++g) {
        const f32x4 bv = *(const f32x4*)(bp + ((k0 + 8 * g + 4 * hi) >> 2) * 1024 + q * 4);
#pragma unroll
        for (int e = 0; e < 4; ++e) st[4 * g + e] += bv[e] + mk[g][e];
      }
      // row max (16 in-register + half-swap)
      float mx = st[0];
#pragma unroll
      for (int r = 1; r < 16; ++r) mx = fmaxf(mx, st[r]);
      mx = fmaxf(mx, __shfl_xor(mx, 32));
      const float mnew = fmaxf(mrun[qt], mx);
      const float alpha = exp2f((mrun[qt] - mnew) * L2E);
      mrun[qt] = mnew;
#pragma unroll
      for (int r = 0; r < 16; ++r) st[r] = exp2f((st[r] - mnew) * L2E);
      float ts = 0.f;
#pragma unroll
      for (int r = 0; r < 16; ++r) ts += st[r];
      ts += __shfl_xor(ts, 32);
      lrun[qt] = lrun[qt] * alpha + ts;
#pragma unroll
      for (int r = 0; r < 16; ++r) Ot[qt][r] *= alpha;
      // pack P (bf16 pairs) and exchange halves
      unsigned c0 = pk2(st[0],  st[1]),  c1 = pk2(st[2],  st[3]);
      unsigned c2 = pk2(st[4],  st[5]),  c3 = pk2(st[6],  st[7]);
      unsigned c4 = pk2(st[8],  st[9]),  c5 = pk2(st[10], st[11]);
      unsigned c6 = pk2(st[12], st[13]), c7 = pk2(st[14], st[15]);
      const unsigned d0 = __shfl_xor(c0, 32), d1 = __shfl_xor(c1, 32);
      const unsigned d2 = __shfl_xor(c2, 32), d3 = __shfl_xor(c3, 32);
      const unsigned d4 = __shfl_xor(c4, 32), d5 = __shfl_xor(c5, 32);
      const unsigned d6 = __shfl_xor(c6, 32), d7 = __shfl_xor(c7, 32);
      u32x4 w0, w1;
      w0[0] = hi ? d2 : c0; w0[1] = hi ? d3 : c1; w0[2] = hi ? c2 : d0; w0[3] = hi ? c3 : d1;
      w1[0] = hi ? d6 : c4; w1[1] = hi ? d7 : c5; w1[2] = hi ? c6 : d4; w1[3] = hi ? c7 : d5;
      const bf16x8 pf0 = __builtin_bit_cast(bf16x8, w0);
      const bf16x8 pf1 = __builtin_bit_cast(bf16x8, w1);
      Ot[qt] = __builtin_amdgcn_mfma_f32_32x32x16_bf16(Vf0, pf0, Ot[qt], 0, 0, 0);
      Ot[qt] = __builtin_amdgcn_mfma_f32_32x32x16_bf16(Vf1, pf1, Ot[qt], 0, 0, 0);
    }
  }
#pragma unroll
  for (int qt = 0; qt < 2; ++qt) {
    const int q = q0 + qt * 32 + l31;
    const float invl = 1.f / lrun[qt];
#pragma unroll
    for (int r = 0; r < 16; ++r) {
      const int dd = (r & 3) + 8 * (r >> 2) + 4 * hi;
      opre[((size_t)n * 256 + q) * 256 + h * 32 + dd] = (__bf16)(Ot[qt][r] * invl);
    }
  }
}

// ---------------- output projection + gate ----------------
__global__ __launch_bounds__(256) void wo_gemm(
    const __bf16* __restrict__ A, const __bf16* __restrict__ Wtw,
    const float* __restrict__ bo, const float* __restrict__ gate,
    float* __restrict__ out)
{
  __shared__ alignas(16) __bf16 Al[128 * LDT];
  __shared__ alignas(16) __bf16 Bl[128 * LDT];
  const int t = threadIdx.x;
  const int wave = t >> 6, lane = t & 63;
  const int l15 = lane & 15, l16 = lane >> 4;
  const int m0 = blockIdx.x * 128;
  const int nloc0 = blockIdx.y * 128;
  const int wm = (wave >> 1) * 64, wn = (wave & 1) * 64;

  f32x4 acc[4][4];
#pragma unroll
  for (int i = 0; i < 4; ++i)
#pragma unroll
    for (int j = 0; j < 4; ++j) acc[i][j] = (f32x4){0.f, 0.f, 0.f, 0.f};

  const int sr = t >> 1, sc = (t & 1) * 32;
  for (int kt = 0; kt < 4; ++kt) {
    const int k0 = kt * 64;
    const bf16x8* ga = (const bf16x8*)(A   + (size_t)(m0 + sr) * 256 + k0 + sc);
    const bf16x8* gb = (const bf16x8*)(Wtw + (size_t)(nloc0 + sr) * 256 + k0 + sc);
    bf16x8* da = (bf16x8*)&Al[sr * LDT + sc];
    bf16x8* db = (bf16x8*)&Bl[sr * LDT + sc];
#pragma unroll
    for (int j = 0; j < 4; ++j) { da[j] = ga[j]; db[j] = gb[j]; }
    __syncthreads();
#pragma unroll
    for (int kk = 0; kk < 2; ++kk) {
      bf16x8 a[4], bfr[4];
#pragma unroll
      for (int mi = 0; mi < 4; ++mi)
        a[mi] = *(const bf16x8*)&Al[(wm + mi * 16 + l15) * LDT + kk * 32 + l16 * 8];
#pragma unroll
      for (int ni = 0; ni < 4; ++ni)
        bfr[ni] = *(const bf16x8*)&Bl[(wn + ni * 16 + l15) * LDT + kk * 32 + l16 * 8];
#pragma unroll
      for (int mi = 0; mi < 4; ++mi)
#pragma unroll
        for (int ni = 0; ni < 4; ++ni)
          acc[mi][ni] = __builtin_amdgcn_mfma_f32_16x16x32_bf16(a[mi], bfr[ni], acc[mi][ni], 0, 0, 0);
    }
    __syncthreads();
  }
#pragma unroll
  for (int mi = 0; mi < 4; ++mi)
#pragma unroll
    for (int ni = 0; ni < 4; ++ni)
#pragma unroll
      for (int r = 0; r < 4; ++r) {
        const int grow = m0 + wm + mi * 16 + l16 * 4 + r;
        const int gcol = nloc0 + wn + ni * 16 + l15;
        const size_t o = (size_t)grow * 256 + gcol;
        out[o] = (acc[mi][ni][r] + bo[gcol]) * gate[o];
      }
}

extern "C" void kernel_launch(void* const* d_in, const int* in_sizes, int n_in,
                              void* d_out, int out_size, void* d_ws, size_t ws_size,
                              hipStream_t stream)
{
  const float* msa  = (const float*)d_in[0];
  const float* pair = (const float*)d_in[1];
  const int*   mask = (const int*)d_in[2];
  const float* ln_g = (const float*)d_in[3];
  const float* ln_b = (const float*)d_in[4];
  const float* Wq = (const float*)d_in[5];  const float* bq = (const float*)d_in[6];
  const float* Wk = (const float*)d_in[7];  const float* bk = (const float*)d_in[8];
  const float* Wv = (const float*)d_in[9];  const float* bv = (const float*)d_in[10];
  const float* Wb = (const float*)d_in[11]; const float* bb = (const float*)d_in[12];
  const float* Wo = (const float*)d_in[13]; const float* bo = (const float*)d_in[14];
  const float* Wg = (const float*)d_in[15]; const float* bg = (const float*)d_in[16];
  float* out = (float*)d_out;

  char* ws = (char*)d_ws;
  __bf16* xn   = (__bf16*)(ws);
  __bf16* qb   = (__bf16*)(ws + 16777216);
  __bf16* kb   = (__bf16*)(ws + 2 * 16777216);
  __bf16* vb   = (__bf16*)(ws + 3 * 16777216);
  __bf16* opre = (__bf16*)(ws + 4 * 16777216);
  __bf16* Wt   = (__bf16*)(ws + 5 * 16777216);                       // 640KB
  float*  gate = (float*)(ws + 5 * 16777216 + 655360);               // 33.5MB
  float*  biasP= (float*)(ws + 5 * 16777216 + 655360 + 33554432);    // 2MB
  float*  maskF= (float*)(ws + 5 * 16777216 + 655360 + 33554432 + 2097152); // 128KB

  hipLaunchKernelGGL(ln_kernel,       dim3(8192),   dim3(256), 0, stream, msa, ln_g, ln_b, xn);
  hipLaunchKernelGGL(bias_kernel,     dim3(256),    dim3(256), 0, stream, pair, Wb, bb, biasP);
  hipLaunchKernelGGL(prep_kernel,     dim3(1280),   dim3(256), 0, stream, Wq, Wk, Wv, Wg, Wo, Wt);
  hipLaunchKernelGGL(maskprep_kernel, dim3(128),    dim3(256), 0, stream, mask, maskF);
  hipLaunchKernelGGL(qkvg_gemm,       dim3(256, 8), dim3(256), 0, stream, xn, Wt, bq, bk, bv, bg, qb, kb, vb, gate);
  hipLaunchKernelGGL(attn_kernel,     dim3(1024),   dim3(256), 0, stream, qb, kb, vb, biasP, maskF, opre);
  hipLaunchKernelGGL(wo_gemm,         dim3(256, 2), dim3(256), 0, stream, opre, Wt + 4 * 65536, bo, gate, out);
}

// Round 4
// 190.541 us; speedup vs baseline: 1.2032x; 1.0208x over previous
//
#include <hip/hip_runtime.h>
#include <hip/hip_bf16.h>

typedef __attribute__((ext_vector_type(4))) float f32x4;
typedef __attribute__((ext_vector_type(16))) float f32x16;
typedef __attribute__((ext_vector_type(8))) __bf16 bf16x8;
typedef __attribute__((ext_vector_type(4))) __bf16 bf16x4;
typedef __attribute__((ext_vector_type(2))) __bf16 bf16x2;
typedef __attribute__((ext_vector_type(4))) unsigned u32x4;

#define LDT 88   // GEMM LDS stride
#define VTS 264  // attn V^T LDS stride
#define L2E 1.4426950408889634f

// ---------------- LayerNorm -> bf16 ----------------
__global__ __launch_bounds__(256) void ln_kernel(
    const float* __restrict__ msa, const float* __restrict__ g,
    const float* __restrict__ b, __bf16* __restrict__ xn)
{
  const int row = blockIdx.x * 4 + (threadIdx.x >> 6);
  const int lane = threadIdx.x & 63;
  const float* src = msa + (size_t)row * 256 + lane * 4;
  f32x4 x = *(const f32x4*)src;
  float s = x[0] + x[1] + x[2] + x[3];
  float s2 = x[0]*x[0] + x[1]*x[1] + x[2]*x[2] + x[3]*x[3];
#pragma unroll
  for (int d = 32; d >= 1; d >>= 1) {
    s  += __shfl_xor(s, d);
    s2 += __shfl_xor(s2, d);
  }
  const float mu  = s * (1.f / 256.f);
  const float inv = rsqrtf(s2 * (1.f / 256.f) - mu * mu + 1e-5f);
  const f32x4 gv = *(const f32x4*)(g + lane * 4);
  const f32x4 bv = *(const f32x4*)(b + lane * 4);
  bf16x4 o;
#pragma unroll
  for (int j = 0; j < 4; ++j) o[j] = (__bf16)((x[j] - mu) * inv * gv[j] + bv[j]);
  *(bf16x4*)(xn + (size_t)row * 256 + lane * 4) = o;
}

// ---- pair bias projection -> biasf[h][i][j] (f32), lane-contiguous stores ----
__global__ __launch_bounds__(256) void bias_kernel(
    const float* __restrict__ pair, const float* __restrict__ Wb,
    const float* __restrict__ bb, float* __restrict__ biasf)
{
  __shared__ float wbs[1024];
  const int t = threadIdx.x;
#pragma unroll
  for (int r2 = 0; r2 < 4; ++r2) wbs[t + 256 * r2] = Wb[t + 256 * r2];
  __syncthreads();
  const int i = blockIdx.x, j = t;   // i = query row, j = key
  const float* src = pair + ((size_t)i * 256 + j) * 128;
  float acc[8];
#pragma unroll
  for (int hh = 0; hh < 8; ++hh) acc[hh] = bb[hh];
  for (int p = 0; p < 128; p += 4) {
    const f32x4 pv = *(const f32x4*)(src + p);
#pragma unroll
    for (int q2 = 0; q2 < 4; ++q2)
#pragma unroll
      for (int hh = 0; hh < 8; ++hh) acc[hh] += pv[q2] * wbs[(p + q2) * 8 + hh];
  }
#pragma unroll
  for (int hh = 0; hh < 8; ++hh)
    biasf[((size_t)hh * 256 + i) * 256 + j] = acc[hh];
}

// ---------------- weight prep: Wt[w][n][k] = W_w[k][n] in bf16 ----------------
__global__ __launch_bounds__(256) void prep_kernel(
    const float* __restrict__ Wq, const float* __restrict__ Wk,
    const float* __restrict__ Wv, const float* __restrict__ Wg,
    const float* __restrict__ Wo, __bf16* __restrict__ Wt)
{
  const int w = blockIdx.x >> 8, n2 = blockIdx.x & 255, k = threadIdx.x;
  const float* W = (w == 0) ? Wq : (w == 1) ? Wk : (w == 2) ? Wv : (w == 3) ? Wg : Wo;
  Wt[((size_t)w * 256 + n2) * 256 + k] = (__bf16)W[(size_t)k * 256 + n2];
}

// ---------------- mask -> additive float ----------------
__global__ __launch_bounds__(256) void maskprep_kernel(
    const int* __restrict__ mask, float* __restrict__ maskF)
{
  const int i = blockIdx.x * 256 + threadIdx.x;
  maskF[i] = mask[i] ? 0.f : -1e9f;
}

// ---------------- fused Q/K/V/Gate GEMM: [32768,256] @ [256,1024] ----------------
// Epilogue: per-wave LDS transpose -> 16B-contiguous stores (head-major q/k/v, bf16 gate).
__global__ __launch_bounds__(256) void qkvg_gemm(
    const __bf16* __restrict__ xn, const __bf16* __restrict__ Wt,
    const float* __restrict__ bq, const float* __restrict__ bk,
    const float* __restrict__ bv, const float* __restrict__ bg,
    __bf16* __restrict__ qb, __bf16* __restrict__ kb,
    __bf16* __restrict__ vb, __bf16* __restrict__ gateb)
{
  __shared__ alignas(16) __bf16 Al[128 * LDT];
  __shared__ alignas(16) __bf16 Bl[128 * LDT];
  const int t = threadIdx.x;
  const int wave = t >> 6, lane = t & 63;
  const int l15 = lane & 15, l16 = lane >> 4;
  const int m0 = blockIdx.x * 128;
  const int bn = blockIdx.y;
  const int w = bn >> 1;
  const int nloc0 = (bn & 1) * 128;
  const __bf16* Wtw = Wt + (size_t)w * 65536;
  const int wm = (wave >> 1) * 64, wn = (wave & 1) * 64;

  f32x4 acc[4][4];
#pragma unroll
  for (int i = 0; i < 4; ++i)
#pragma unroll
    for (int j = 0; j < 4; ++j) acc[i][j] = (f32x4){0.f, 0.f, 0.f, 0.f};

  const int sr = t >> 1, sc = (t & 1) * 32;
  for (int kt = 0; kt < 4; ++kt) {
    const int k0 = kt * 64;
    const bf16x8* ga = (const bf16x8*)(xn  + (size_t)(m0 + sr) * 256 + k0 + sc);
    const bf16x8* gb = (const bf16x8*)(Wtw + (size_t)(nloc0 + sr) * 256 + k0 + sc);
    bf16x8* da = (bf16x8*)&Al[sr * LDT + sc];
    bf16x8* db = (bf16x8*)&Bl[sr * LDT + sc];
#pragma unroll
    for (int j = 0; j < 4; ++j) { da[j] = ga[j]; db[j] = gb[j]; }
    __syncthreads();
#pragma unroll
    for (int kk = 0; kk < 2; ++kk) {
      bf16x8 a[4], bfr[4];
#pragma unroll
      for (int mi = 0; mi < 4; ++mi)
        a[mi] = *(const bf16x8*)&Al[(wm + mi * 16 + l15) * LDT + kk * 32 + l16 * 8];
#pragma unroll
      for (int ni = 0; ni < 4; ++ni)
        bfr[ni] = *(const bf16x8*)&Bl[(wn + ni * 16 + l15) * LDT + kk * 32 + l16 * 8];
#pragma unroll
      for (int mi = 0; mi < 4; ++mi)
#pragma unroll
        for (int ni = 0; ni < 4; ++ni)
          acc[mi][ni] = __builtin_amdgcn_mfma_f32_16x16x32_bf16(a[mi], bfr[ni], acc[mi][ni], 0, 0, 0);
    }
    __syncthreads();
  }

  // ---- epilogue: wave-local LDS transpose, then coalesced 16B stores ----
  const float* bias_arr = (w == 0) ? bq : (w == 1) ? bk : (w == 2) ? bv : bg;
  float bnis[4];
#pragma unroll
  for (int ni = 0; ni < 4; ++ni) bnis[ni] = bias_arr[nloc0 + wn + ni * 16 + l15];

  __bf16* Tw = ((wave < 2) ? Al : Bl) + (wave & 1) * (64 * 72);
#pragma unroll
  for (int mi = 0; mi < 4; ++mi)
#pragma unroll
    for (int ni = 0; ni < 4; ++ni)
#pragma unroll
      for (int r = 0; r < 4; ++r) {
        const float v = acc[mi][ni][r] + bnis[ni];
        __bf16 val;
        if (w == 0)      val = (__bf16)(v * 0.1767766952966369f); // 1/sqrt(32)
        else if (w == 3) val = (__bf16)(1.f / (1.f + __expf(-v)));
        else             val = (__bf16)v;
        Tw[(mi * 16 + l16 * 4 + r) * 72 + ni * 16 + l15] = val;
      }
  // wave-local RAW: HW lgkmcnt ordering suffices, no barrier.
  bf16x8 rowv[8];
#pragma unroll
  for (int c = 0; c < 8; ++c) rowv[c] = *(const bf16x8*)&Tw[lane * 72 + c * 8];

  const int grow = m0 + wm + lane;
  const int n = grow >> 8, i2 = grow & 255;
  if (w < 3) {
    __bf16* db2 = (w == 0) ? qb : (w == 1) ? kb : vb;
    const int hA = (nloc0 + wn) >> 5;
#pragma unroll
    for (int hh = 0; hh < 2; ++hh) {
      __bf16* dst = db2 + (((size_t)n * 8 + hA + hh) * 256 + i2) * 32;
#pragma unroll
      for (int c = 0; c < 4; ++c) *(bf16x8*)(dst + c * 8) = rowv[hh * 4 + c];
    }
  } else {
    __bf16* dst = gateb + (size_t)grow * 256 + nloc0 + wn;
#pragma unroll
    for (int c = 0; c < 8; ++c) *(bf16x8*)(dst + c * 8) = rowv[c];
  }
}

// ---------------- flash attention: swapped 32x32 MFMA, in-register softmax ----------------
__device__ __forceinline__ unsigned pk2(float a, float b) {
  bf16x2 t; t[0] = (__bf16)a; t[1] = (__bf16)b;
  return __builtin_bit_cast(unsigned, t);
}

__global__ __launch_bounds__(256, 4) void attn_kernel(
    const __bf16* __restrict__ qb, const __bf16* __restrict__ kb,
    const __bf16* __restrict__ vb, const float* __restrict__ biasf,
    const float* __restrict__ maskF, __bf16* __restrict__ opre)
{
  __shared__ alignas(16) __bf16 Vt[32 * VTS];   // V^T [dh][key]
  const int t = threadIdx.x, wave = t >> 6, lane = t & 63;
  const int l31 = lane & 31, hi = lane >> 5;
  const int nh = blockIdx.x, n = nh >> 3, h = nh & 7;
  const __bf16* kbh = kb + (size_t)nh * 8192;
  const __bf16* qbh = qb + (size_t)nh * 8192;

  { // stage V^T (one-time)
    const bf16x8* vs = (const bf16x8*)(vb + (size_t)nh * 8192 + t * 32);
    bf16x8 vv[4];
#pragma unroll
    for (int j = 0; j < 4; ++j) vv[j] = vs[j];
#pragma unroll
    for (int j = 0; j < 4; ++j)
#pragma unroll
      for (int e = 0; e < 8; ++e) Vt[(j * 8 + e) * VTS + t] = vv[j][e];
  }
  __syncthreads();

  const int q0 = wave * 64;
  bf16x8 Qf[2][2];
#pragma unroll
  for (int qt = 0; qt < 2; ++qt)
#pragma unroll
    for (int sl = 0; sl < 2; ++sl)
      Qf[qt][sl] = *(const bf16x8*)(qbh + (size_t)(q0 + qt * 32 + l31) * 32 + sl * 16 + hi * 8);

  f32x16 Ot[2];
#pragma unroll
  for (int r = 0; r < 16; ++r) { Ot[0][r] = 0.f; Ot[1][r] = 0.f; }
  float mrun[2] = {-1e30f, -1e30f}, lrun[2] = {0.f, 0.f};

  const float* bp = biasf + (size_t)h * 65536;
  const float* mf = maskF + n * 256;

#pragma unroll 2
  for (int k0 = 0; k0 < 256; k0 += 32) {
    const bf16x8 Kf0 = *(const bf16x8*)(kbh + (size_t)(k0 + l31) * 32 + hi * 8);
    const bf16x8 Kf1 = *(const bf16x8*)(kbh + (size_t)(k0 + l31) * 32 + 16 + hi * 8);
    const bf16x8 Vf0 = *(const bf16x8*)&Vt[l31 * VTS + k0 + hi * 8];
    const bf16x8 Vf1 = *(const bf16x8*)&Vt[l31 * VTS + k0 + 16 + hi * 8];
    f32x4 mk[4];
#pragma unroll
    for (int g = 0; g < 4; ++g) mk[g] = *(const f32x4*)(mf + k0 + 8 * g + 4 * hi);

#pragma unroll
    for (int qt = 0; qt < 2; ++qt) {
      f32x16 st;
#pragma unroll
      for (int r = 0; r < 16; ++r) st[r] = 0.f;
      st = __builtin_amdgcn_mfma_f32_32x32x16_bf16(Kf0, Qf[qt][0], st, 0, 0, 0);
      st = __builtin_amdgcn_mfma_f32_32x32x16_bf16(Kf1, Qf[qt][1], st, 0, 0, 0);
      const int q = q0 + qt * 32 + l31;
#pragma unroll
      for (int g = 0; g < 4; ++g) {
        const f32x4 bv = *(const f32x4*)(bp + (size_t)q * 256 + k0 + 8 * g + 4 * hi);
#pragma unroll
        for (int e = 0; e < 4; ++e) st[4 * g + e] += bv[e] + mk[g][e];
      }
      float mx = st[0];
#pragma unroll
      for (int r = 1; r < 16; ++r) mx = fmaxf(mx, st[r]);
      mx = fmaxf(mx, __shfl_xor(mx, 32));
      const float mnew = fmaxf(mrun[qt], mx);
      const float alpha = exp2f((mrun[qt] - mnew) * L2E);
      mrun[qt] = mnew;
#pragma unroll
      for (int r = 0; r < 16; ++r) st[r] = exp2f((st[r] - mnew) * L2E);
      float ts = 0.f;
#pragma unroll
      for (int r = 0; r < 16; ++r) ts += st[r];
      ts += __shfl_xor(ts, 32);
      lrun[qt] = lrun[qt] * alpha + ts;
#pragma unroll
      for (int r = 0; r < 16; ++r) Ot[qt][r] *= alpha;
      unsigned c0 = pk2(st[0],  st[1]),  c1 = pk2(st[2],  st[3]);
      unsigned c2 = pk2(st[4],  st[5]),  c3 = pk2(st[6],  st[7]);
      unsigned c4 = pk2(st[8],  st[9]),  c5 = pk2(st[10], st[11]);
      unsigned c6 = pk2(st[12], st[13]), c7 = pk2(st[14], st[15]);
      const unsigned d0 = __shfl_xor(c0, 32), d1 = __shfl_xor(c1, 32);
      const unsigned d2 = __shfl_xor(c2, 32), d3 = __shfl_xor(c3, 32);
      const unsigned d4 = __shfl_xor(c4, 32), d5 = __shfl_xor(c5, 32);
      const unsigned d6 = __shfl_xor(c6, 32), d7 = __shfl_xor(c7, 32);
      u32x4 w0, w1;
      w0[0] = hi ? d2 : c0; w0[1] = hi ? d3 : c1; w0[2] = hi ? c2 : d0; w0[3] = hi ? c3 : d1;
      w1[0] = hi ? d6 : c4; w1[1] = hi ? d7 : c5; w1[2] = hi ? c6 : d4; w1[3] = hi ? c7 : d5;
      const bf16x8 pf0 = __builtin_bit_cast(bf16x8, w0);
      const bf16x8 pf1 = __builtin_bit_cast(bf16x8, w1);
      Ot[qt] = __builtin_amdgcn_mfma_f32_32x32x16_bf16(Vf0, pf0, Ot[qt], 0, 0, 0);
      Ot[qt] = __builtin_amdgcn_mfma_f32_32x32x16_bf16(Vf1, pf1, Ot[qt], 0, 0, 0);
    }
  }

  // ---- epilogue: opre h-major [h][n][q][dh]; shuffle-exchange -> 2x dwordx4/lane/qt ----
#pragma unroll
  for (int qt = 0; qt < 2; ++qt) {
    const float invl = 1.f / lrun[qt];
    unsigned P[4][2], R[4][2];
#pragma unroll
    for (int c = 0; c < 4; ++c) {
      P[c][0] = pk2(Ot[qt][4*c]     * invl, Ot[qt][4*c + 1] * invl);
      P[c][1] = pk2(Ot[qt][4*c + 2] * invl, Ot[qt][4*c + 3] * invl);
    }
#pragma unroll
    for (int c = 0; c < 4; ++c) {
      R[c][0] = __shfl_xor(P[c][0], 32);
      R[c][1] = __shfl_xor(P[c][1], 32);
    }
    u32x4 s0, s1;
    s0[0] = hi ? R[2][0] : P[0][0]; s0[1] = hi ? R[2][1] : P[0][1];
    s0[2] = hi ? P[2][0] : R[0][0]; s0[3] = hi ? P[2][1] : R[0][1];
    s1[0] = hi ? R[3][0] : P[1][0]; s1[1] = hi ? R[3][1] : P[1][1];
    s1[2] = hi ? P[3][0] : R[1][0]; s1[3] = hi ? P[3][1] : R[1][1];
    const int q = q0 + qt * 32 + l31;
    __bf16* dst = opre + (((size_t)h * 128 + n) * 256 + q) * 32 + hi * 16;
    *(u32x4*)dst = s0;
    *(u32x4*)(dst + 8) = s1;
  }
}

// ---------------- output projection + gate (A = opre h-major, gate bf16) ----------------
__global__ __launch_bounds__(256) void wo_gemm(
    const __bf16* __restrict__ A, const __bf16* __restrict__ Wtw,
    const float* __restrict__ bo, const __bf16* __restrict__ gateb,
    float* __restrict__ out)
{
  __shared__ alignas(16) __bf16 Al[128 * LDT];
  __shared__ alignas(16) __bf16 Bl[128 * LDT];
  const int t = threadIdx.x;
  const int wave = t >> 6, lane = t & 63;
  const int l15 = lane & 15, l16 = lane >> 4;
  const int m0 = blockIdx.x * 128;
  const int nloc0 = blockIdx.y * 128;
  const int wm = (wave >> 1) * 64, wn = (wave & 1) * 64;

  f32x4 acc[4][4];
#pragma unroll
  for (int i = 0; i < 4; ++i)
#pragma unroll
    for (int j = 0; j < 4; ++j) acc[i][j] = (f32x4){0.f, 0.f, 0.f, 0.f};

  const int sr = t >> 1, sc = (t & 1) * 32;
  const int an = (m0 + sr) >> 8, aq = (m0 + sr) & 255;
  for (int kt = 0; kt < 4; ++kt) {
    const int kc = kt * 64 + sc;          // multiple of 32
    const int ah = kc >> 5;
    const bf16x8* ga = (const bf16x8*)(A + (((size_t)ah * 128 + an) * 256 + aq) * 32);
    const bf16x8* gb = (const bf16x8*)(Wtw + (size_t)(nloc0 + sr) * 256 + kc);
    bf16x8* da = (bf16x8*)&Al[sr * LDT + sc];
    bf16x8* db = (bf16x8*)&Bl[sr * LDT + sc];
#pragma unroll
    for (int j = 0; j < 4; ++j) { da[j] = ga[j]; db[j] = gb[j]; }
    __syncthreads();
#pragma unroll
    for (int kk = 0; kk < 2; ++kk) {
      bf16x8 a[4], bfr[4];
#pragma unroll
      for (int mi = 0; mi < 4; ++mi)
        a[mi] = *(const bf16x8*)&Al[(wm + mi * 16 + l15) * LDT + kk * 32 + l16 * 8];
#pragma unroll
      for (int ni = 0; ni < 4; ++ni)
        bfr[ni] = *(const bf16x8*)&Bl[(wn + ni * 16 + l15) * LDT + kk * 32 + l16 * 8];
#pragma unroll
      for (int mi = 0; mi < 4; ++mi)
#pragma unroll
        for (int ni = 0; ni < 4; ++ni)
          acc[mi][ni] = __builtin_amdgcn_mfma_f32_16x16x32_bf16(a[mi], bfr[ni], acc[mi][ni], 0, 0, 0);
    }
    __syncthreads();
  }

  // ---- epilogue: bias + gate, wave-local LDS transpose (2 passes), 16B stores ----
  float bov[4];
#pragma unroll
  for (int ni = 0; ni < 4; ++ni) bov[ni] = bo[nloc0 + wn + ni * 16 + l15];
  float* Twf = (float*)(((wave < 2) ? Al : Bl)) + (wave & 1) * (32 * 68);
  const int lrow = lane >> 1, lcol = (lane & 1) * 32;
#pragma unroll
  for (int half = 0; half < 2; ++half) {
#pragma unroll
    for (int m2 = 0; m2 < 2; ++m2) {
      const int mi = half * 2 + m2;
#pragma unroll
      for (int ni = 0; ni < 4; ++ni)
#pragma unroll
        for (int r = 0; r < 4; ++r) {
          const int grow = m0 + wm + mi * 16 + l16 * 4 + r;
          const int gcol = nloc0 + wn + ni * 16 + l15;
          const float gt = (float)gateb[(size_t)grow * 256 + gcol];
          Twf[(m2 * 16 + l16 * 4 + r) * 68 + ni * 16 + l15] =
              (acc[mi][ni][r] + bov[ni]) * gt;
        }
    }
    const int grow2 = m0 + wm + half * 32 + lrow;
    float* dst = out + (size_t)grow2 * 256 + nloc0 + wn + lcol;
#pragma unroll
    for (int c = 0; c < 8; ++c)
      *(f32x4*)(dst + c * 4) = *(const f32x4*)&Twf[lrow * 68 + lcol + c * 4];
  }
}

extern "C" void kernel_launch(void* const* d_in, const int* in_sizes, int n_in,
                              void* d_out, int out_size, void* d_ws, size_t ws_size,
                              hipStream_t stream)
{
  const float* msa  = (const float*)d_in[0];
  const float* pair = (const float*)d_in[1];
  const int*   mask = (const int*)d_in[2];
  const float* ln_g = (const float*)d_in[3];
  const float* ln_b = (const float*)d_in[4];
  const float* Wq = (const float*)d_in[5];  const float* bq = (const float*)d_in[6];
  const float* Wk = (const float*)d_in[7];  const float* bk = (const float*)d_in[8];
  const float* Wv = (const float*)d_in[9];  const float* bv = (const float*)d_in[10];
  const float* Wb = (const float*)d_in[11]; const float* bb = (const float*)d_in[12];
  const float* Wo = (const float*)d_in[13]; const float* bo = (const float*)d_in[14];
  const float* Wg = (const float*)d_in[15]; const float* bg = (const float*)d_in[16];
  float* out = (float*)d_out;

  char* ws = (char*)d_ws;
  __bf16* xn    = (__bf16*)(ws);
  __bf16* qb    = (__bf16*)(ws + 16777216);
  __bf16* kb    = (__bf16*)(ws + 2 * 16777216);
  __bf16* vb    = (__bf16*)(ws + 3 * 16777216);
  __bf16* opre  = (__bf16*)(ws + 4 * 16777216);
  __bf16* Wt    = (__bf16*)(ws + 5 * 16777216);                      // 640KB
  __bf16* gateb = (__bf16*)(ws + 5 * 16777216 + 655360);             // 16.8MB
  float*  biasf = (float*)(ws + 5 * 16777216 + 655360 + 16777216);   // 2MB
  float*  maskF = (float*)(ws + 5 * 16777216 + 655360 + 16777216 + 2097152); // 128KB

  hipLaunchKernelGGL(ln_kernel,       dim3(8192),   dim3(256), 0, stream, msa, ln_g, ln_b, xn);
  hipLaunchKernelGGL(bias_kernel,     dim3(256),    dim3(256), 0, stream, pair, Wb, bb, biasf);
  hipLaunchKernelGGL(prep_kernel,     dim3(1280),   dim3(256), 0, stream, Wq, Wk, Wv, Wg, Wo, Wt);
  hipLaunchKernelGGL(maskprep_kernel, dim3(128),    dim3(256), 0, stream, mask, maskF);
  hipLaunchKernelGGL(qkvg_gemm,       dim3(256, 8), dim3(256), 0, stream, xn, Wt, bq, bk, bv, bg, qb, kb, vb, gateb);
  hipLaunchKernelGGL(attn_kernel,     dim3(1024),   dim3(256), 0, stream, qb, kb, vb, biasf, maskF, opre);
  hipLaunchKernelGGL(wo_gemm,         dim3(256, 2), dim3(256), 0, stream, opre, Wt + 4 * 65536, bo, gateb, out);
}

// Round 5
// 158.276 us; speedup vs baseline: 1.4485x; 1.2039x over previous
//
#include <hip/hip_runtime.h>
#include <hip/hip_bf16.h>

typedef __attribute__((ext_vector_type(4))) float f32x4;
typedef __attribute__((ext_vector_type(16))) float f32x16;
typedef __attribute__((ext_vector_type(8))) __bf16 bf16x8;
typedef __attribute__((ext_vector_type(4))) __bf16 bf16x4;
typedef __attribute__((ext_vector_type(2))) __bf16 bf16x2;
typedef __attribute__((ext_vector_type(4))) unsigned u32x4;

#define LDT 88   // GEMM LDS stride
#define VTS 264  // attn V^T LDS stride
#define L2E 1.4426950408889634f

// ---------------- LayerNorm -> bf16 ----------------
__global__ __launch_bounds__(256) void ln_kernel(
    const float* __restrict__ msa, const float* __restrict__ g,
    const float* __restrict__ b, __bf16* __restrict__ xn)
{
  const int row = blockIdx.x * 4 + (threadIdx.x >> 6);
  const int lane = threadIdx.x & 63;
  const float* src = msa + (size_t)row * 256 + lane * 4;
  f32x4 x = *(const f32x4*)src;
  float s = x[0] + x[1] + x[2] + x[3];
  float s2 = x[0]*x[0] + x[1]*x[1] + x[2]*x[2] + x[3]*x[3];
#pragma unroll
  for (int d = 32; d >= 1; d >>= 1) {
    s  += __shfl_xor(s, d);
    s2 += __shfl_xor(s2, d);
  }
  const float mu  = s * (1.f / 256.f);
  const float inv = rsqrtf(s2 * (1.f / 256.f) - mu * mu + 1e-5f);
  const f32x4 gv = *(const f32x4*)(g + lane * 4);
  const f32x4 bv = *(const f32x4*)(b + lane * 4);
  bf16x4 o;
#pragma unroll
  for (int j = 0; j < 4; ++j) o[j] = (__bf16)((x[j] - mu) * inv * gv[j] + bv[j]);
  *(bf16x4*)(xn + (size_t)row * 256 + lane * 4) = o;
}

// ---- pair bias projection -> biasf[h][i][j] (f32), lane-contiguous stores ----
__global__ __launch_bounds__(256) void bias_kernel(
    const float* __restrict__ pair, const float* __restrict__ Wb,
    const float* __restrict__ bb, float* __restrict__ biasf)
{
  __shared__ float wbs[1024];
  const int t = threadIdx.x;
#pragma unroll
  for (int r2 = 0; r2 < 4; ++r2) wbs[t + 256 * r2] = Wb[t + 256 * r2];
  __syncthreads();
  const int i = blockIdx.x, j = t;   // i = query row, j = key
  const float* src = pair + ((size_t)i * 256 + j) * 128;
  float acc[8];
#pragma unroll
  for (int hh = 0; hh < 8; ++hh) acc[hh] = bb[hh];
  for (int p = 0; p < 128; p += 4) {
    const f32x4 pv = *(const f32x4*)(src + p);
#pragma unroll
    for (int q2 = 0; q2 < 4; ++q2)
#pragma unroll
      for (int hh = 0; hh < 8; ++hh) acc[hh] += pv[q2] * wbs[(p + q2) * 8 + hh];
  }
#pragma unroll
  for (int hh = 0; hh < 8; ++hh)
    biasf[((size_t)hh * 256 + i) * 256 + j] = acc[hh];
}

// ---------------- weight prep: Wt[w][n][k] = W_w[k][n] in bf16 ----------------
__global__ __launch_bounds__(256) void prep_kernel(
    const float* __restrict__ Wq, const float* __restrict__ Wk,
    const float* __restrict__ Wv, const float* __restrict__ Wg,
    const float* __restrict__ Wo, __bf16* __restrict__ Wt)
{
  const int w = blockIdx.x >> 8, n2 = blockIdx.x & 255, k = threadIdx.x;
  const float* W = (w == 0) ? Wq : (w == 1) ? Wk : (w == 2) ? Wv : (w == 3) ? Wg : Wo;
  Wt[((size_t)w * 256 + n2) * 256 + k] = (__bf16)W[(size_t)k * 256 + n2];
}

// ---------------- mask -> additive float ----------------
__global__ __launch_bounds__(256) void maskprep_kernel(
    const int* __restrict__ mask, float* __restrict__ maskF)
{
  const int i = blockIdx.x * 256 + threadIdx.x;
  maskF[i] = mask[i] ? 0.f : -1e9f;
}

// ---------------- fused Q/K/V/Gate GEMM: [32768,256] @ [256,1024] ----------------
__global__ __launch_bounds__(256) void qkvg_gemm(
    const __bf16* __restrict__ xn, const __bf16* __restrict__ Wt,
    const float* __restrict__ bq, const float* __restrict__ bk,
    const float* __restrict__ bv, const float* __restrict__ bg,
    __bf16* __restrict__ qb, __bf16* __restrict__ kb,
    __bf16* __restrict__ vb, __bf16* __restrict__ gateb)
{
  __shared__ alignas(16) __bf16 Al[128 * LDT];
  __shared__ alignas(16) __bf16 Bl[128 * LDT];
  const int t = threadIdx.x;
  const int wave = t >> 6, lane = t & 63;
  const int l15 = lane & 15, l16 = lane >> 4;
  const int m0 = blockIdx.x * 128;
  const int bn = blockIdx.y;
  const int w = bn >> 1;
  const int nloc0 = (bn & 1) * 128;
  const __bf16* Wtw = Wt + (size_t)w * 65536;
  const int wm = (wave >> 1) * 64, wn = (wave & 1) * 64;

  f32x4 acc[4][4];
#pragma unroll
  for (int i = 0; i < 4; ++i)
#pragma unroll
    for (int j = 0; j < 4; ++j) acc[i][j] = (f32x4){0.f, 0.f, 0.f, 0.f};

  const int sr = t >> 1, sc = (t & 1) * 32;
  for (int kt = 0; kt < 4; ++kt) {
    const int k0 = kt * 64;
    const bf16x8* ga = (const bf16x8*)(xn  + (size_t)(m0 + sr) * 256 + k0 + sc);
    const bf16x8* gb = (const bf16x8*)(Wtw + (size_t)(nloc0 + sr) * 256 + k0 + sc);
    bf16x8* da = (bf16x8*)&Al[sr * LDT + sc];
    bf16x8* db = (bf16x8*)&Bl[sr * LDT + sc];
#pragma unroll
    for (int j = 0; j < 4; ++j) { da[j] = ga[j]; db[j] = gb[j]; }
    __syncthreads();
#pragma unroll
    for (int kk = 0; kk < 2; ++kk) {
      bf16x8 a[4], bfr[4];
#pragma unroll
      for (int mi = 0; mi < 4; ++mi)
        a[mi] = *(const bf16x8*)&Al[(wm + mi * 16 + l15) * LDT + kk * 32 + l16 * 8];
#pragma unroll
      for (int ni = 0; ni < 4; ++ni)
        bfr[ni] = *(const bf16x8*)&Bl[(wn + ni * 16 + l15) * LDT + kk * 32 + l16 * 8];
#pragma unroll
      for (int mi = 0; mi < 4; ++mi)
#pragma unroll
        for (int ni = 0; ni < 4; ++ni)
          acc[mi][ni] = __builtin_amdgcn_mfma_f32_16x16x32_bf16(a[mi], bfr[ni], acc[mi][ni], 0, 0, 0);
    }
    __syncthreads();
  }

  // ---- epilogue: wave-local LDS transpose, then coalesced 16B stores ----
  const float* bias_arr = (w == 0) ? bq : (w == 1) ? bk : (w == 2) ? bv : bg;
  float bnis[4];
#pragma unroll
  for (int ni = 0; ni < 4; ++ni) bnis[ni] = bias_arr[nloc0 + wn + ni * 16 + l15];

  __bf16* Tw = ((wave < 2) ? Al : Bl) + (wave & 1) * (64 * 72);
#pragma unroll
  for (int mi = 0; mi < 4; ++mi)
#pragma unroll
    for (int ni = 0; ni < 4; ++ni)
#pragma unroll
      for (int r = 0; r < 4; ++r) {
        const float v = acc[mi][ni][r] + bnis[ni];
        __bf16 val;
        if (w == 0)      val = (__bf16)(v * 0.1767766952966369f); // 1/sqrt(32)
        else if (w == 3) val = (__bf16)(1.f / (1.f + __expf(-v)));
        else             val = (__bf16)v;
        Tw[(mi * 16 + l16 * 4 + r) * 72 + ni * 16 + l15] = val;
      }
  bf16x8 rowv[8];
#pragma unroll
  for (int c = 0; c < 8; ++c) rowv[c] = *(const bf16x8*)&Tw[lane * 72 + c * 8];

  const int grow = m0 + wm + lane;
  const int n = grow >> 8, i2 = grow & 255;
  if (w < 3) {
    __bf16* db2 = (w == 0) ? qb : (w == 1) ? kb : vb;
    const int hA = (nloc0 + wn) >> 5;
#pragma unroll
    for (int hh = 0; hh < 2; ++hh) {
      __bf16* dst = db2 + (((size_t)n * 8 + hA + hh) * 256 + i2) * 32;
#pragma unroll
      for (int c = 0; c < 4; ++c) *(bf16x8*)(dst + c * 8) = rowv[hh * 4 + c];
    }
  } else {
    __bf16* dst = gateb + (size_t)grow * 256 + nloc0 + wn;
#pragma unroll
    for (int c = 0; c < 8; ++c) *(bf16x8*)(dst + c * 8) = rowv[c];
  }
}

// ---------------- flash attention: swapped 32x32 MFMA, in-register softmax ----------------
__device__ __forceinline__ unsigned pk2(float a, float b) {
  bf16x2 t; t[0] = (__bf16)a; t[1] = (__bf16)b;
  return __builtin_bit_cast(unsigned, t);
}

__global__ __launch_bounds__(256) void attn_kernel(
    const __bf16* __restrict__ qb, const __bf16* __restrict__ kb,
    const __bf16* __restrict__ vb, const float* __restrict__ biasf,
    const float* __restrict__ maskF, __bf16* __restrict__ opre)
{
  __shared__ alignas(16) __bf16 Vt[32 * VTS];   // V^T [dh][key]
  const int t = threadIdx.x, wave = t >> 6, lane = t & 63;
  const int l31 = lane & 31, hi = lane >> 5;
  const int nh = blockIdx.x, n = nh >> 3, h = nh & 7;
  const __bf16* kbh = kb + (size_t)nh * 8192;
  const __bf16* qbh = qb + (size_t)nh * 8192;

  { // stage V^T (one-time)
    const bf16x8* vs = (const bf16x8*)(vb + (size_t)nh * 8192 + t * 32);
    bf16x8 vv[4];
#pragma unroll
    for (int j = 0; j < 4; ++j) vv[j] = vs[j];
#pragma unroll
    for (int j = 0; j < 4; ++j)
#pragma unroll
      for (int e = 0; e < 8; ++e) Vt[(j * 8 + e) * VTS + t] = vv[j][e];
  }
  __syncthreads();

  const int q0 = wave * 64;
  bf16x8 Qf[2][2];
#pragma unroll
  for (int qt = 0; qt < 2; ++qt)
#pragma unroll
    for (int sl = 0; sl < 2; ++sl)
      Qf[qt][sl] = *(const bf16x8*)(qbh + (size_t)(q0 + qt * 32 + l31) * 32 + sl * 16 + hi * 8);

  f32x16 Ot[2];
#pragma unroll
  for (int r = 0; r < 16; ++r) { Ot[0][r] = 0.f; Ot[1][r] = 0.f; }
  float mrun[2] = {-1e30f, -1e30f}, lrun[2] = {0.f, 0.f};

  const float* bp = biasf + (size_t)h * 65536;
  const float* mf = maskF + n * 256;

#pragma unroll 1
  for (int k0 = 0; k0 < 256; k0 += 32) {
    const bf16x8 Kf0 = *(const bf16x8*)(kbh + (size_t)(k0 + l31) * 32 + hi * 8);
    const bf16x8 Kf1 = *(const bf16x8*)(kbh + (size_t)(k0 + l31) * 32 + 16 + hi * 8);
    const bf16x8 Vf0 = *(const bf16x8*)&Vt[l31 * VTS + k0 + hi * 8];
    const bf16x8 Vf1 = *(const bf16x8*)&Vt[l31 * VTS + k0 + 16 + hi * 8];
    f32x4 mk[4];
#pragma unroll
    for (int g = 0; g < 4; ++g) mk[g] = *(const f32x4*)(mf + k0 + 8 * g + 4 * hi);

#pragma unroll
    for (int qt = 0; qt < 2; ++qt) {
      f32x16 st;
#pragma unroll
      for (int r = 0; r < 16; ++r) st[r] = 0.f;
      st = __builtin_amdgcn_mfma_f32_32x32x16_bf16(Kf0, Qf[qt][0], st, 0, 0, 0);
      st = __builtin_amdgcn_mfma_f32_32x32x16_bf16(Kf1, Qf[qt][1], st, 0, 0, 0);
      const int q = q0 + qt * 32 + l31;
#pragma unroll
      for (int g = 0; g < 4; ++g) {
        const f32x4 bv = *(const f32x4*)(bp + (size_t)q * 256 + k0 + 8 * g + 4 * hi);
#pragma unroll
        for (int e = 0; e < 4; ++e) st[4 * g + e] += bv[e] + mk[g][e];
      }
      float mx = st[0];
#pragma unroll
      for (int r = 1; r < 16; ++r) mx = fmaxf(mx, st[r]);
      mx = fmaxf(mx, __shfl_xor(mx, 32));
      const float mnew = fmaxf(mrun[qt], mx);
      const float alpha = exp2f((mrun[qt] - mnew) * L2E);
      mrun[qt] = mnew;
#pragma unroll
      for (int r = 0; r < 16; ++r) st[r] = exp2f((st[r] - mnew) * L2E);
      float ts = 0.f;
#pragma unroll
      for (int r = 0; r < 16; ++r) ts += st[r];
      ts += __shfl_xor(ts, 32);
      lrun[qt] = lrun[qt] * alpha + ts;
#pragma unroll
      for (int r = 0; r < 16; ++r) Ot[qt][r] *= alpha;
      unsigned c0 = pk2(st[0],  st[1]),  c1 = pk2(st[2],  st[3]);
      unsigned c2 = pk2(st[4],  st[5]),  c3 = pk2(st[6],  st[7]);
      unsigned c4 = pk2(st[8],  st[9]),  c5 = pk2(st[10], st[11]);
      unsigned c6 = pk2(st[12], st[13]), c7 = pk2(st[14], st[15]);
      const unsigned d0 = __shfl_xor(c0, 32), d1 = __shfl_xor(c1, 32);
      const unsigned d2 = __shfl_xor(c2, 32), d3 = __shfl_xor(c3, 32);
      const unsigned d4 = __shfl_xor(c4, 32), d5 = __shfl_xor(c5, 32);
      const unsigned d6 = __shfl_xor(c6, 32), d7 = __shfl_xor(c7, 32);
      u32x4 w0, w1;
      w0[0] = hi ? d2 : c0; w0[1] = hi ? d3 : c1; w0[2] = hi ? c2 : d0; w0[3] = hi ? c3 : d1;
      w1[0] = hi ? d6 : c4; w1[1] = hi ? d7 : c5; w1[2] = hi ? c6 : d4; w1[3] = hi ? c7 : d5;
      const bf16x8 pf0 = __builtin_bit_cast(bf16x8, w0);
      const bf16x8 pf1 = __builtin_bit_cast(bf16x8, w1);
      Ot[qt] = __builtin_amdgcn_mfma_f32_32x32x16_bf16(Vf0, pf0, Ot[qt], 0, 0, 0);
      Ot[qt] = __builtin_amdgcn_mfma_f32_32x32x16_bf16(Vf1, pf1, Ot[qt], 0, 0, 0);
    }
  }

  // ---- epilogue: opre h-major [h][n][q][dh]; shuffle-exchange -> 2x dwordx4/lane/qt ----
#pragma unroll
  for (int qt = 0; qt < 2; ++qt) {
    const float invl = 1.f / lrun[qt];
    unsigned P[4][2], R[4][2];
#pragma unroll
    for (int c = 0; c < 4; ++c) {
      P[c][0] = pk2(Ot[qt][4*c]     * invl, Ot[qt][4*c + 1] * invl);
      P[c][1] = pk2(Ot[qt][4*c + 2] * invl, Ot[qt][4*c + 3] * invl);
    }
#pragma unroll
    for (int c = 0; c < 4; ++c) {
      R[c][0] = __shfl_xor(P[c][0], 32);
      R[c][1] = __shfl_xor(P[c][1], 32);
    }
    u32x4 s0, s1;
    s0[0] = hi ? R[2][0] : P[0][0]; s0[1] = hi ? R[2][1] : P[0][1];
    s0[2] = hi ? P[2][0] : R[0][0]; s0[3] = hi ? P[2][1] : R[0][1];
    s1[0] = hi ? R[3][0] : P[1][0]; s1[1] = hi ? R[3][1] : P[1][1];
    s1[2] = hi ? P[3][0] : R[1][0]; s1[3] = hi ? P[3][1] : R[1][1];
    const int q = q0 + qt * 32 + l31;
    __bf16* dst = opre + (((size_t)h * 128 + n) * 256 + q) * 32 + hi * 16;
    *(u32x4*)dst = s0;
    *(u32x4*)(dst + 8) = s1;
  }
}

// ---------------- output projection + gate (A = opre h-major, gate bf16) ----------------
__global__ __launch_bounds__(256) void wo_gemm(
    const __bf16* __restrict__ A, const __bf16* __restrict__ Wtw,
    const float* __restrict__ bo, const __bf16* __restrict__ gateb,
    float* __restrict__ out)
{
  __shared__ alignas(16) __bf16 Al[128 * LDT];
  __shared__ alignas(16) __bf16 Bl[128 * LDT];
  const int t = threadIdx.x;
  const int wave = t >> 6, lane = t & 63;
  const int l15 = lane & 15, l16 = lane >> 4;
  const int m0 = blockIdx.x * 128;
  const int nloc0 = blockIdx.y * 128;
  const int wm = (wave >> 1) * 64, wn = (wave & 1) * 64;

  f32x4 acc[4][4];
#pragma unroll
  for (int i = 0; i < 4; ++i)
#pragma unroll
    for (int j = 0; j < 4; ++j) acc[i][j] = (f32x4){0.f, 0.f, 0.f, 0.f};

  const int sr = t >> 1, sc = (t & 1) * 32;
  const int an = (m0 + sr) >> 8, aq = (m0 + sr) & 255;
  for (int kt = 0; kt < 4; ++kt) {
    const int kc = kt * 64 + sc;          // multiple of 32
    const int ah = kc >> 5;
    const bf16x8* ga = (const bf16x8*)(A + (((size_t)ah * 128 + an) * 256 + aq) * 32);
    const bf16x8* gb = (const bf16x8*)(Wtw + (size_t)(nloc0 + sr) * 256 + kc);
    bf16x8* da = (bf16x8*)&Al[sr * LDT + sc];
    bf16x8* db = (bf16x8*)&Bl[sr * LDT + sc];
#pragma unroll
    for (int j = 0; j < 4; ++j) { da[j] = ga[j]; db[j] = gb[j]; }
    __syncthreads();
#pragma unroll
    for (int kk = 0; kk < 2; ++kk) {
      bf16x8 a[4], bfr[4];
#pragma unroll
      for (int mi = 0; mi < 4; ++mi)
        a[mi] = *(const bf16x8*)&Al[(wm + mi * 16 + l15) * LDT + kk * 32 + l16 * 8];
#pragma unroll
      for (int ni = 0; ni < 4; ++ni)
        bfr[ni] = *(const bf16x8*)&Bl[(wn + ni * 16 + l15) * LDT + kk * 32 + l16 * 8];
#pragma unroll
      for (int mi = 0; mi < 4; ++mi)
#pragma unroll
        for (int ni = 0; ni < 4; ++ni)
          acc[mi][ni] = __builtin_amdgcn_mfma_f32_16x16x32_bf16(a[mi], bfr[ni], acc[mi][ni], 0, 0, 0);
    }
    __syncthreads();
  }

  // ---- epilogue: bias + gate, wave-local LDS transpose (2 passes), 16B stores ----
  float bov[4];
#pragma unroll
  for (int ni = 0; ni < 4; ++ni) bov[ni] = bo[nloc0 + wn + ni * 16 + l15];
  float* Twf = (float*)(((wave < 2) ? Al : Bl)) + (wave & 1) * (32 * 68);
  const int lrow = lane >> 1, lcol = (lane & 1) * 32;
#pragma unroll
  for (int half = 0; half < 2; ++half) {
#pragma unroll
    for (int m2 = 0; m2 < 2; ++m2) {
      const int mi = half * 2 + m2;
#pragma unroll
      for (int ni = 0; ni < 4; ++ni)
#pragma unroll
        for (int r = 0; r < 4; ++r) {
          const int grow = m0 + wm + mi * 16 + l16 * 4 + r;
          const int gcol = nloc0 + wn + ni * 16 + l15;
          const float gt = (float)gateb[(size_t)grow * 256 + gcol];
          Twf[(m2 * 16 + l16 * 4 + r) * 68 + ni * 16 + l15] =
              (acc[mi][ni][r] + bov[ni]) * gt;
        }
    }
    const int grow2 = m0 + wm + half * 32 + lrow;
    float* dst = out + (size_t)grow2 * 256 + nloc0 + wn + lcol;
#pragma unroll
    for (int c = 0; c < 8; ++c)
      *(f32x4*)(dst + c * 4) = *(const f32x4*)&Twf[lrow * 68 + lcol + c * 4];
  }
}

extern "C" void kernel_launch(void* const* d_in, const int* in_sizes, int n_in,
                              void* d_out, int out_size, void* d_ws, size_t ws_size,
                              hipStream_t stream)
{
  const float* msa  = (const float*)d_in[0];
  const float* pair = (const float*)d_in[1];
  const int*   mask = (const int*)d_in[2];
  const float* ln_g = (const float*)d_in[3];
  const float* ln_b = (const float*)d_in[4];
  const float* Wq = (const float*)d_in[5];  const float* bq = (const float*)d_in[6];
  const float* Wk = (const float*)d_in[7];  const float* bk = (const float*)d_in[8];
  const float* Wv = (const float*)d_in[9];  const float* bv = (const float*)d_in[10];
  const float* Wb = (const float*)d_in[11]; const float* bb = (const float*)d_in[12];
  const float* Wo = (const float*)d_in[13]; const float* bo = (const float*)d_in[14];
  const float* Wg = (const float*)d_in[15]; const float* bg = (const float*)d_in[16];
  float* out = (float*)d_out;

  char* ws = (char*)d_ws;
  __bf16* xn    = (__bf16*)(ws);
  __bf16* qb    = (__bf16*)(ws + 16777216);
  __bf16* kb    = (__bf16*)(ws + 2 * 16777216);
  __bf16* vb    = (__bf16*)(ws + 3 * 16777216);
  __bf16* opre  = (__bf16*)(ws + 4 * 16777216);
  __bf16* Wt    = (__bf16*)(ws + 5 * 16777216);                      // 640KB
  __bf16* gateb = (__bf16*)(ws + 5 * 16777216 + 655360);             // 16.8MB
  float*  biasf = (float*)(ws + 5 * 16777216 + 655360 + 16777216);   // 2MB
  float*  maskF = (float*)(ws + 5 * 16777216 + 655360 + 16777216 + 2097152); // 128KB

  hipLaunchKernelGGL(ln_kernel,       dim3(8192),   dim3(256), 0, stream, msa, ln_g, ln_b, xn);
  hipLaunchKernelGGL(bias_kernel,     dim3(256),    dim3(256), 0, stream, pair, Wb, bb, biasf);
  hipLaunchKernelGGL(prep_kernel,     dim3(1280),   dim3(256), 0, stream, Wq, Wk, Wv, Wg, Wo, Wt);
  hipLaunchKernelGGL(maskprep_kernel, dim3(128),    dim3(256), 0, stream, mask, maskF);
  hipLaunchKernelGGL(qkvg_gemm,       dim3(256, 8), dim3(256), 0, stream, xn, Wt, bq, bk, bv, bg, qb, kb, vb, gateb);
  hipLaunchKernelGGL(attn_kernel,     dim3(1024),   dim3(256), 0, stream, qb, kb, vb, biasf, maskF, opre);
  hipLaunchKernelGGL(wo_gemm,         dim3(256, 2), dim3(256), 0, stream, opre, Wt + 4 * 65536, bo, gateb, out);
}

// Round 6
// 145.526 us; speedup vs baseline: 1.5754x; 1.0876x over previous
//
#include <hip/hip_runtime.h>
#include <hip/hip_bf16.h>

typedef __attribute__((ext_vector_type(4))) float f32x4;
typedef __attribute__((ext_vector_type(16))) float f32x16;
typedef __attribute__((ext_vector_type(8))) __bf16 bf16x8;
typedef __attribute__((ext_vector_type(4))) __bf16 bf16x4;
typedef __attribute__((ext_vector_type(2))) __bf16 bf16x2;
typedef __attribute__((ext_vector_type(4))) unsigned u32x4;

#define VTS 264  // attn V^T LDS stride
#define L2E 1.4426950408889634f

#define GLOAD_LDS16(g, l) __builtin_amdgcn_global_load_lds( \
    (const __attribute__((address_space(1))) void*)(g),     \
    (__attribute__((address_space(3))) void*)(l), 16, 0, 0)

// ---------------- LayerNorm -> bf16 ----------------
__global__ __launch_bounds__(256) void ln_kernel(
    const float* __restrict__ msa, const float* __restrict__ g,
    const float* __restrict__ b, __bf16* __restrict__ xn)
{
  const int row = blockIdx.x * 4 + (threadIdx.x >> 6);
  const int lane = threadIdx.x & 63;
  const float* src = msa + (size_t)row * 256 + lane * 4;
  f32x4 x = *(const f32x4*)src;
  float s = x[0] + x[1] + x[2] + x[3];
  float s2 = x[0]*x[0] + x[1]*x[1] + x[2]*x[2] + x[3]*x[3];
#pragma unroll
  for (int d = 32; d >= 1; d >>= 1) {
    s  += __shfl_xor(s, d);
    s2 += __shfl_xor(s2, d);
  }
  const float mu  = s * (1.f / 256.f);
  const float inv = rsqrtf(s2 * (1.f / 256.f) - mu * mu + 1e-5f);
  const f32x4 gv = *(const f32x4*)(g + lane * 4);
  const f32x4 bv = *(const f32x4*)(b + lane * 4);
  bf16x4 o;
#pragma unroll
  for (int j = 0; j < 4; ++j) o[j] = (__bf16)((x[j] - mu) * inv * gv[j] + bv[j]);
  *(bf16x4*)(xn + (size_t)row * 256 + lane * 4) = o;
}

// ---- pair bias projection -> biasf[h][i][j] (f32, pre-scaled by log2(e)) ----
__global__ __launch_bounds__(256) void bias_kernel(
    const float* __restrict__ pair, const float* __restrict__ Wb,
    const float* __restrict__ bb, float* __restrict__ biasf)
{
  __shared__ float wbs[1024];
  const int t = threadIdx.x;
#pragma unroll
  for (int r2 = 0; r2 < 4; ++r2) wbs[t + 256 * r2] = Wb[t + 256 * r2];
  __syncthreads();
  const int i = blockIdx.x, j = t;   // i = query row, j = key
  const float* src = pair + ((size_t)i * 256 + j) * 128;
  float acc[8];
#pragma unroll
  for (int hh = 0; hh < 8; ++hh) acc[hh] = bb[hh];
  for (int p = 0; p < 128; p += 4) {
    const f32x4 pv = *(const f32x4*)(src + p);
#pragma unroll
    for (int q2 = 0; q2 < 4; ++q2)
#pragma unroll
      for (int hh = 0; hh < 8; ++hh) acc[hh] += pv[q2] * wbs[(p + q2) * 8 + hh];
  }
#pragma unroll
  for (int hh = 0; hh < 8; ++hh)
    biasf[((size_t)hh * 256 + i) * 256 + j] = acc[hh] * L2E;
}

// ---------------- weight prep: Wt[w][n][k] = W_w[k][n] in bf16 ----------------
__global__ __launch_bounds__(256) void prep_kernel(
    const float* __restrict__ Wq, const float* __restrict__ Wk,
    const float* __restrict__ Wv, const float* __restrict__ Wg,
    const float* __restrict__ Wo, __bf16* __restrict__ Wt)
{
  const int w = blockIdx.x >> 8, n2 = blockIdx.x & 255, k = threadIdx.x;
  const float* W = (w == 0) ? Wq : (w == 1) ? Wk : (w == 2) ? Wv : (w == 3) ? Wg : Wo;
  Wt[((size_t)w * 256 + n2) * 256 + k] = (__bf16)W[(size_t)k * 256 + n2];
}

// ---------------- mask -> additive float (log2-domain -inf) ----------------
__global__ __launch_bounds__(256) void maskprep_kernel(
    const int* __restrict__ mask, float* __restrict__ maskF)
{
  const int i = blockIdx.x * 256 + threadIdx.x;
  maskF[i] = mask[i] ? 0.f : -1e9f;
}

// ---------------- fused Q/K/V/Gate GEMM: [32768,256] @ [256,1024] ----------------
// global_load_lds(16B) staging, linear LDS [128][64], XOR-swizzled (src+read).
__global__ __launch_bounds__(256) void qkvg_gemm(
    const __bf16* __restrict__ xn, const __bf16* __restrict__ Wt,
    const float* __restrict__ bq, const float* __restrict__ bk,
    const float* __restrict__ bv, const float* __restrict__ bg,
    __bf16* __restrict__ qb, __bf16* __restrict__ kb,
    __bf16* __restrict__ vb, __bf16* __restrict__ gateb)
{
  __shared__ alignas(16) __bf16 Al[128 * 64];
  __shared__ alignas(16) __bf16 Bl[128 * 64];
  const int t = threadIdx.x;
  const int wave = t >> 6, lane = t & 63;
  const int l15 = lane & 15, l16 = lane >> 4;
  const int m0 = blockIdx.x * 128;
  const int bn = blockIdx.y;
  const int w = bn >> 1;
  const int nloc0 = (bn & 1) * 128;
  const __bf16* Wtw = Wt + (size_t)w * 65536;
  const int wm = (wave >> 1) * 64, wn = (wave & 1) * 64;

  // staging geometry: inst i of wave covers rows wave*32+i*8 .. +8
  const int srow = (lane >> 3);               // 0..7 within 8-row group
  const int chunk = ((lane & 7) ^ srow) * 8;  // inverse-swizzled source col (elems)

  f32x4 acc[4][4];
#pragma unroll
  for (int i = 0; i < 4; ++i)
#pragma unroll
    for (int j = 0; j < 4; ++j) acc[i][j] = (f32x4){0.f, 0.f, 0.f, 0.f};

  for (int kt = 0; kt < 4; ++kt) {
    const int k0 = kt * 64;
#pragma unroll
    for (int i = 0; i < 4; ++i) {
      const int row = wave * 32 + i * 8 + srow;
      GLOAD_LDS16(xn  + (size_t)(m0 + row) * 256 + k0 + chunk,  &Al[(wave * 4 + i) * 512]);
      GLOAD_LDS16(Wtw + (size_t)(nloc0 + row) * 256 + k0 + chunk, &Bl[(wave * 4 + i) * 512]);
    }
    __syncthreads();
#pragma unroll
    for (int kk = 0; kk < 2; ++kk) {
      bf16x8 a[4], bfr[4];
#pragma unroll
      for (int mi = 0; mi < 4; ++mi) {
        const int row = wm + mi * 16 + l15;
        a[mi] = *(const bf16x8*)&Al[row * 64 + ((kk * 32 + l16 * 8) ^ ((row & 7) << 3))];
      }
#pragma unroll
      for (int ni = 0; ni < 4; ++ni) {
        const int row = wn + ni * 16 + l15;
        bfr[ni] = *(const bf16x8*)&Bl[row * 64 + ((kk * 32 + l16 * 8) ^ ((row & 7) << 3))];
      }
#pragma unroll
      for (int mi = 0; mi < 4; ++mi)
#pragma unroll
        for (int ni = 0; ni < 4; ++ni)
          acc[mi][ni] = __builtin_amdgcn_mfma_f32_16x16x32_bf16(a[mi], bfr[ni], acc[mi][ni], 0, 0, 0);
    }
    __syncthreads();
  }

  // ---- epilogue: direct stores (write-combining handles sub-line stores) ----
  const float* bias_arr = (w == 0) ? bq : (w == 1) ? bk : (w == 2) ? bv : bg;
  float bnis[4];
#pragma unroll
  for (int ni = 0; ni < 4; ++ni) bnis[ni] = bias_arr[nloc0 + wn + ni * 16 + l15];
  const float qscale = 0.17677669529663687f * L2E;  // 1/sqrt(32) * log2(e)

#pragma unroll
  for (int mi = 0; mi < 4; ++mi)
#pragma unroll
    for (int ni = 0; ni < 4; ++ni)
#pragma unroll
      for (int r = 0; r < 4; ++r) {
        const int grow = m0 + wm + mi * 16 + l16 * 4 + r;
        const int gcol = nloc0 + wn + ni * 16 + l15;
        const float v = acc[mi][ni][r] + bnis[ni];
        const int n = grow >> 8, i2 = grow & 255, h = gcol >> 5, dh = gcol & 31;
        const size_t hoff = (((size_t)n * 8 + h) * 256 + i2) * 32 + dh;
        if (w == 0)      qb[hoff] = (__bf16)(v * qscale);
        else if (w == 1) kb[hoff] = (__bf16)v;
        else if (w == 2) vb[hoff] = (__bf16)v;
        else gateb[(size_t)grow * 256 + gcol] = (__bf16)(1.f / (1.f + __expf(-v)));
      }
}

// ---------------- flash attention: no-shift softmax, 1 q-tile/wave ----------------
__device__ __forceinline__ unsigned pk2(float a, float b) {
  bf16x2 t; t[0] = (__bf16)a; t[1] = (__bf16)b;
  return __builtin_bit_cast(unsigned, t);
}

__global__ __launch_bounds__(256) void attn_kernel(
    const __bf16* __restrict__ qb, const __bf16* __restrict__ kb,
    const __bf16* __restrict__ vb, const float* __restrict__ biasf,
    const float* __restrict__ maskF, __bf16* __restrict__ opre)
{
  __shared__ alignas(16) __bf16 Vt[32 * VTS];   // V^T [dh][key]
  const int t = threadIdx.x, wave = t >> 6, lane = t & 63;
  const int l31 = lane & 31, hi = lane >> 5;
  const int bid = blockIdx.x, nh = bid >> 1, half = bid & 1;
  const int n = nh >> 3, h = nh & 7;
  const __bf16* kbh = kb + (size_t)nh * 8192;
  const __bf16* qbh = qb + (size_t)nh * 8192;

  { // stage V^T (one-time)
    const bf16x8* vs = (const bf16x8*)(vb + (size_t)nh * 8192 + t * 32);
    bf16x8 vv[4];
#pragma unroll
    for (int j = 0; j < 4; ++j) vv[j] = vs[j];
#pragma unroll
    for (int j = 0; j < 4; ++j)
#pragma unroll
      for (int e = 0; e < 8; ++e) Vt[(j * 8 + e) * VTS + t] = vv[j][e];
  }
  __syncthreads();

  const int q0 = half * 128 + wave * 32;
  bf16x8 Qf[2];
#pragma unroll
  for (int sl = 0; sl < 2; ++sl)
    Qf[sl] = *(const bf16x8*)(qbh + (size_t)(q0 + l31) * 32 + sl * 16 + hi * 8);

  f32x16 Ot;
#pragma unroll
  for (int r = 0; r < 16; ++r) Ot[r] = 0.f;
  float lrun = 0.f;

  const float* bp = biasf + (size_t)h * 65536;
  const float* mf = maskF + n * 256;
  const int q = q0 + l31;

#pragma unroll 1
  for (int k0 = 0; k0 < 256; k0 += 32) {
    const bf16x8 Kf0 = *(const bf16x8*)(kbh + (size_t)(k0 + l31) * 32 + hi * 8);
    const bf16x8 Kf1 = *(const bf16x8*)(kbh + (size_t)(k0 + l31) * 32 + 16 + hi * 8);
    const bf16x8 Vf0 = *(const bf16x8*)&Vt[l31 * VTS + k0 + hi * 8];
    const bf16x8 Vf1 = *(const bf16x8*)&Vt[l31 * VTS + k0 + 16 + hi * 8];

    f32x16 st;
#pragma unroll
    for (int r = 0; r < 16; ++r) st[r] = 0.f;
    st = __builtin_amdgcn_mfma_f32_32x32x16_bf16(Kf0, Qf[0], st, 0, 0, 0);
    st = __builtin_amdgcn_mfma_f32_32x32x16_bf16(Kf1, Qf[1], st, 0, 0, 0);
#pragma unroll
    for (int g = 0; g < 4; ++g) {
      const f32x4 bv = *(const f32x4*)(bp + (size_t)q * 256 + k0 + 8 * g + 4 * hi);
      const f32x4 mk = *(const f32x4*)(mf + k0 + 8 * g + 4 * hi);
#pragma unroll
      for (int e = 0; e < 4; ++e) st[4 * g + e] = exp2f(st[4 * g + e] + bv[e] + mk[e]);
    }
    float ts = 0.f;
#pragma unroll
    for (int r = 0; r < 16; ++r) ts += st[r];
    ts += __shfl_xor(ts, 32);
    lrun += ts;

    unsigned c0 = pk2(st[0],  st[1]),  c1 = pk2(st[2],  st[3]);
    unsigned c2 = pk2(st[4],  st[5]),  c3 = pk2(st[6],  st[7]);
    unsigned c4 = pk2(st[8],  st[9]),  c5 = pk2(st[10], st[11]);
    unsigned c6 = pk2(st[12], st[13]), c7 = pk2(st[14], st[15]);
    const unsigned d0 = __shfl_xor(c0, 32), d1 = __shfl_xor(c1, 32);
    const unsigned d2 = __shfl_xor(c2, 32), d3 = __shfl_xor(c3, 32);
    const unsigned d4 = __shfl_xor(c4, 32), d5 = __shfl_xor(c5, 32);
    const unsigned d6 = __shfl_xor(c6, 32), d7 = __shfl_xor(c7, 32);
    u32x4 w0, w1;
    w0[0] = hi ? d2 : c0; w0[1] = hi ? d3 : c1; w0[2] = hi ? c2 : d0; w0[3] = hi ? c3 : d1;
    w1[0] = hi ? d6 : c4; w1[1] = hi ? d7 : c5; w1[2] = hi ? c6 : d4; w1[3] = hi ? c7 : d5;
    const bf16x8 pf0 = __builtin_bit_cast(bf16x8, w0);
    const bf16x8 pf1 = __builtin_bit_cast(bf16x8, w1);
    Ot = __builtin_amdgcn_mfma_f32_32x32x16_bf16(Vf0, pf0, Ot, 0, 0, 0);
    Ot = __builtin_amdgcn_mfma_f32_32x32x16_bf16(Vf1, pf1, Ot, 0, 0, 0);
  }

  // ---- epilogue: opre h-major [h][n][q][dh] ----
  {
    const float invl = 1.f / lrun;
    unsigned P[4][2], R[4][2];
#pragma unroll
    for (int c = 0; c < 4; ++c) {
      P[c][0] = pk2(Ot[4*c]     * invl, Ot[4*c + 1] * invl);
      P[c][1] = pk2(Ot[4*c + 2] * invl, Ot[4*c + 3] * invl);
    }
#pragma unroll
    for (int c = 0; c < 4; ++c) {
      R[c][0] = __shfl_xor(P[c][0], 32);
      R[c][1] = __shfl_xor(P[c][1], 32);
    }
    u32x4 s0, s1;
    s0[0] = hi ? R[2][0] : P[0][0]; s0[1] = hi ? R[2][1] : P[0][1];
    s0[2] = hi ? P[2][0] : R[0][0]; s0[3] = hi ? P[2][1] : R[0][1];
    s1[0] = hi ? R[3][0] : P[1][0]; s1[1] = hi ? R[3][1] : P[1][1];
    s1[2] = hi ? P[3][0] : R[1][0]; s1[3] = hi ? P[3][1] : R[1][1];
    __bf16* dst = opre + (((size_t)h * 128 + n) * 256 + q) * 32 + hi * 16;
    *(u32x4*)dst = s0;
    *(u32x4*)(dst + 8) = s1;
  }
}

// ---------------- output projection + gate ----------------
__global__ __launch_bounds__(256) void wo_gemm(
    const __bf16* __restrict__ A, const __bf16* __restrict__ Wtw,
    const float* __restrict__ bo, const __bf16* __restrict__ gateb,
    float* __restrict__ out)
{
  __shared__ alignas(16) __bf16 Al[128 * 64];
  __shared__ alignas(16) __bf16 Bl[128 * 64];
  const int t = threadIdx.x;
  const int wave = t >> 6, lane = t & 63;
  const int l15 = lane & 15, l16 = lane >> 4;
  const int m0 = blockIdx.x * 128;
  const int nloc0 = blockIdx.y * 128;
  const int wm = (wave >> 1) * 64, wn = (wave & 1) * 64;

  const int srow = (lane >> 3);
  const int chunk = ((lane & 7) ^ srow) * 8;

  f32x4 acc[4][4];
#pragma unroll
  for (int i = 0; i < 4; ++i)
#pragma unroll
    for (int j = 0; j < 4; ++j) acc[i][j] = (f32x4){0.f, 0.f, 0.f, 0.f};

  for (int kt = 0; kt < 4; ++kt) {
    const int k0 = kt * 64;
#pragma unroll
    for (int i = 0; i < 4; ++i) {
      const int row = wave * 32 + i * 8 + srow;
      const int m = m0 + row;
      const int kg = k0 + chunk;
      // A[m][k] = opre[h=kg>>5][n=m>>8][q=m&255][dh=kg&31]
      GLOAD_LDS16(A + (size_t)(kg >> 5) * 1048576 + (size_t)(m >> 8) * 8192
                    + (m & 255) * 32 + (kg & 31),
                  &Al[(wave * 4 + i) * 512]);
      GLOAD_LDS16(Wtw + (size_t)(nloc0 + row) * 256 + kg, &Bl[(wave * 4 + i) * 512]);
    }
    __syncthreads();
#pragma unroll
    for (int kk = 0; kk < 2; ++kk) {
      bf16x8 a[4], bfr[4];
#pragma unroll
      for (int mi = 0; mi < 4; ++mi) {
        const int row = wm + mi * 16 + l15;
        a[mi] = *(const bf16x8*)&Al[row * 64 + ((kk * 32 + l16 * 8) ^ ((row & 7) << 3))];
      }
#pragma unroll
      for (int ni = 0; ni < 4; ++ni) {
        const int row = wn + ni * 16 + l15;
        bfr[ni] = *(const bf16x8*)&Bl[row * 64 + ((kk * 32 + l16 * 8) ^ ((row & 7) << 3))];
      }
#pragma unroll
      for (int mi = 0; mi < 4; ++mi)
#pragma unroll
        for (int ni = 0; ni < 4; ++ni)
          acc[mi][ni] = __builtin_amdgcn_mfma_f32_16x16x32_bf16(a[mi], bfr[ni], acc[mi][ni], 0, 0, 0);
    }
    __syncthreads();
  }

  // ---- epilogue: bias + gate, direct stores ----
  float bov[4];
#pragma unroll
  for (int ni = 0; ni < 4; ++ni) bov[ni] = bo[nloc0 + wn + ni * 16 + l15];
#pragma unroll
  for (int mi = 0; mi < 4; ++mi)
#pragma unroll
    for (int ni = 0; ni < 4; ++ni)
#pragma unroll
      for (int r = 0; r < 4; ++r) {
        const int grow = m0 + wm + mi * 16 + l16 * 4 + r;
        const int gcol = nloc0 + wn + ni * 16 + l15;
        const size_t o = (size_t)grow * 256 + gcol;
        out[o] = (acc[mi][ni][r] + bov[ni]) * (float)gateb[o];
      }
}

extern "C" void kernel_launch(void* const* d_in, const int* in_sizes, int n_in,
                              void* d_out, int out_size, void* d_ws, size_t ws_size,
                              hipStream_t stream)
{
  const float* msa  = (const float*)d_in[0];
  const float* pair = (const float*)d_in[1];
  const int*   mask = (const int*)d_in[2];
  const float* ln_g = (const float*)d_in[3];
  const float* ln_b = (const float*)d_in[4];
  const float* Wq = (const float*)d_in[5];  const float* bq = (const float*)d_in[6];
  const float* Wk = (const float*)d_in[7];  const float* bk = (const float*)d_in[8];
  const float* Wv = (const float*)d_in[9];  const float* bv = (const float*)d_in[10];
  const float* Wb = (const float*)d_in[11]; const float* bb = (const float*)d_in[12];
  const float* Wo = (const float*)d_in[13]; const float* bo = (const float*)d_in[14];
  const float* Wg = (const float*)d_in[15]; const float* bg = (const float*)d_in[16];
  float* out = (float*)d_out;

  char* ws = (char*)d_ws;
  __bf16* xn    = (__bf16*)(ws);
  __bf16* qb    = (__bf16*)(ws + 16777216);
  __bf16* kb    = (__bf16*)(ws + 2 * 16777216);
  __bf16* vb    = (__bf16*)(ws + 3 * 16777216);
  __bf16* opre  = (__bf16*)(ws + 4 * 16777216);
  __bf16* Wt    = (__bf16*)(ws + 5 * 16777216);                      // 640KB
  __bf16* gateb = (__bf16*)(ws + 5 * 16777216 + 655360);             // 16.8MB
  float*  biasf = (float*)(ws + 5 * 16777216 + 655360 + 16777216);   // 2MB
  float*  maskF = (float*)(ws + 5 * 16777216 + 655360 + 16777216 + 2097152); // 128KB

  hipLaunchKernelGGL(ln_kernel,       dim3(8192),   dim3(256), 0, stream, msa, ln_g, ln_b, xn);
  hipLaunchKernelGGL(bias_kernel,     dim3(256),    dim3(256), 0, stream, pair, Wb, bb, biasf);
  hipLaunchKernelGGL(prep_kernel,     dim3(1280),   dim3(256), 0, stream, Wq, Wk, Wv, Wg, Wo, Wt);
  hipLaunchKernelGGL(maskprep_kernel, dim3(128),    dim3(256), 0, stream, mask, maskF);
  hipLaunchKernelGGL(qkvg_gemm,       dim3(256, 8), dim3(256), 0, stream, xn, Wt, bq, bk, bv, bg, qb, kb, vb, gateb);
  hipLaunchKernelGGL(attn_kernel,     dim3(2048),   dim3(256), 0, stream, qb, kb, vb, biasf, maskF, opre);
  hipLaunchKernelGGL(wo_gemm,         dim3(256, 2), dim3(256), 0, stream, opre, Wt + 4 * 65536, bo, gateb, out);
}

// Round 10
// 138.196 us; speedup vs baseline: 1.6589x; 1.0530x over previous
//
#include <hip/hip_runtime.h>
#include <hip/hip_bf16.h>

typedef __attribute__((ext_vector_type(4))) float f32x4;
typedef __attribute__((ext_vector_type(16))) float f32x16;
typedef __attribute__((ext_vector_type(8))) __bf16 bf16x8;
typedef __attribute__((ext_vector_type(4))) __bf16 bf16x4;
typedef __attribute__((ext_vector_type(2))) __bf16 bf16x2;
typedef __attribute__((ext_vector_type(4))) unsigned u32x4;
typedef __attribute__((ext_vector_type(2))) unsigned u32x2;

#define VTS 264  // attn V^T LDS stride
#define L2E 1.4426950408889634f

#define GLOAD_LDS16(g, l) __builtin_amdgcn_global_load_lds( \
    (const __attribute__((address_space(1))) void*)(g),     \
    (__attribute__((address_space(3))) void*)(l), 16, 0, 0)

// exchange: a' = (a_lo, b_lo) ; b' = (a_hi, b_hi)   [lane<32 half | lane>=32 half]
// NOTE: operands must be DISTINCT values — the HW instruction RMWs two registers;
// self-aliased operands (SUM32's old form) corrupt the result. Sum uses shfl.
#if __has_builtin(__builtin_amdgcn_permlane32_swap)
#define SWP(a, b) { u32x2 _r = __builtin_amdgcn_permlane32_swap((a), (b), false, false); \
                    (a) = _r[0]; (b) = _r[1]; }
#else
#define SWP(a, b) { unsigned _sa = __shfl_xor((a), 32), _sb = __shfl_xor((b), 32); \
                    unsigned _na = hi ? _sb : (a); (b) = hi ? (b) : _sa; (a) = _na; }
#endif
#define SUM32(ts, lrun) { (lrun) += (ts) + __shfl_xor((ts), 32); }

// ---------------- LayerNorm -> bf16 ----------------
__global__ __launch_bounds__(256) void ln_kernel(
    const float* __restrict__ msa, const float* __restrict__ g,
    const float* __restrict__ b, __bf16* __restrict__ xn)
{
  const int row = blockIdx.x * 4 + (threadIdx.x >> 6);
  const int lane = threadIdx.x & 63;
  const float* src = msa + (size_t)row * 256 + lane * 4;
  f32x4 x = *(const f32x4*)src;
  float s = x[0] + x[1] + x[2] + x[3];
  float s2 = x[0]*x[0] + x[1]*x[1] + x[2]*x[2] + x[3]*x[3];
#pragma unroll
  for (int d = 32; d >= 1; d >>= 1) {
    s  += __shfl_xor(s, d);
    s2 += __shfl_xor(s2, d);
  }
  const float mu  = s * (1.f / 256.f);
  const float inv = rsqrtf(s2 * (1.f / 256.f) - mu * mu + 1e-5f);
  const f32x4 gv = *(const f32x4*)(g + lane * 4);
  const f32x4 bv = *(const f32x4*)(b + lane * 4);
  bf16x4 o;
#pragma unroll
  for (int j = 0; j < 4; ++j) o[j] = (__bf16)((x[j] - mu) * inv * gv[j] + bv[j]);
  *(bf16x4*)(xn + (size_t)row * 256 + lane * 4) = o;
}

// ---- pair bias projection -> biasf[h][i][j] (f32, L2E-prescaled) ----
__global__ __launch_bounds__(256) void bias_kernel(
    const float* __restrict__ pair, const float* __restrict__ Wb,
    const float* __restrict__ bb, float* __restrict__ biasf)
{
  __shared__ float wbs[1024];
  const int t = threadIdx.x;
#pragma unroll
  for (int r2 = 0; r2 < 4; ++r2) wbs[t + 256 * r2] = Wb[t + 256 * r2];
  __syncthreads();
  const int i = blockIdx.x, j = t;   // i = query row, j = key
  const float* src = pair + ((size_t)i * 256 + j) * 128;
  float acc[8];
#pragma unroll
  for (int hh = 0; hh < 8; ++hh) acc[hh] = bb[hh];
  for (int p = 0; p < 128; p += 4) {
    const f32x4 pv = *(const f32x4*)(src + p);
#pragma unroll
    for (int q2 = 0; q2 < 4; ++q2)
#pragma unroll
      for (int hh = 0; hh < 8; ++hh) acc[hh] += pv[q2] * wbs[(p + q2) * 8 + hh];
  }
#pragma unroll
  for (int hh = 0; hh < 8; ++hh)
    biasf[((size_t)hh * 256 + i) * 256 + j] = acc[hh] * L2E;
}

// ---------------- weight prep: Wt[w][n][k] = W_w[k][n] in bf16 ----------------
__global__ __launch_bounds__(256) void prep_kernel(
    const float* __restrict__ Wq, const float* __restrict__ Wk,
    const float* __restrict__ Wv, const float* __restrict__ Wg,
    const float* __restrict__ Wo, __bf16* __restrict__ Wt)
{
  const int w = blockIdx.x >> 8, n2 = blockIdx.x & 255, k = threadIdx.x;
  const float* W = (w == 0) ? Wq : (w == 1) ? Wk : (w == 2) ? Wv : (w == 3) ? Wg : Wo;
  Wt[((size_t)w * 256 + n2) * 256 + k] = (__bf16)W[(size_t)k * 256 + n2];
}

// ---------------- fused Q/K/V/Gate GEMM (unchanged) ----------------
__global__ __launch_bounds__(256) void qkvg_gemm(
    const __bf16* __restrict__ xn, const __bf16* __restrict__ Wt,
    const float* __restrict__ bq, const float* __restrict__ bk,
    const float* __restrict__ bv, const float* __restrict__ bg,
    __bf16* __restrict__ qb, __bf16* __restrict__ kb,
    __bf16* __restrict__ vb, __bf16* __restrict__ gateb)
{
  __shared__ alignas(16) __bf16 Al[128 * 64];
  __shared__ alignas(16) __bf16 Bl[128 * 64];
  const int t = threadIdx.x;
  const int wave = t >> 6, lane = t & 63;
  const int l15 = lane & 15, l16 = lane >> 4;
  const int m0 = blockIdx.x * 128;
  const int bn = blockIdx.y;
  const int w = bn >> 1;
  const int nloc0 = (bn & 1) * 128;
  const __bf16* Wtw = Wt + (size_t)w * 65536;
  const int wm = (wave >> 1) * 64, wn = (wave & 1) * 64;

  const int srow = (lane >> 3);
  const int chunk = ((lane & 7) ^ srow) * 8;

  f32x4 acc[4][4];
#pragma unroll
  for (int i = 0; i < 4; ++i)
#pragma unroll
    for (int j = 0; j < 4; ++j) acc[i][j] = (f32x4){0.f, 0.f, 0.f, 0.f};

  for (int kt = 0; kt < 4; ++kt) {
    const int k0 = kt * 64;
#pragma unroll
    for (int i = 0; i < 4; ++i) {
      const int row = wave * 32 + i * 8 + srow;
      GLOAD_LDS16(xn  + (size_t)(m0 + row) * 256 + k0 + chunk,  &Al[(wave * 4 + i) * 512]);
      GLOAD_LDS16(Wtw + (size_t)(nloc0 + row) * 256 + k0 + chunk, &Bl[(wave * 4 + i) * 512]);
    }
    __syncthreads();
#pragma unroll
    for (int kk = 0; kk < 2; ++kk) {
      bf16x8 a[4], bfr[4];
#pragma unroll
      for (int mi = 0; mi < 4; ++mi) {
        const int row = wm + mi * 16 + l15;
        a[mi] = *(const bf16x8*)&Al[row * 64 + ((kk * 32 + l16 * 8) ^ ((row & 7) << 3))];
      }
#pragma unroll
      for (int ni = 0; ni < 4; ++ni) {
        const int row = wn + ni * 16 + l15;
        bfr[ni] = *(const bf16x8*)&Bl[row * 64 + ((kk * 32 + l16 * 8) ^ ((row & 7) << 3))];
      }
#pragma unroll
      for (int mi = 0; mi < 4; ++mi)
#pragma unroll
        for (int ni = 0; ni < 4; ++ni)
          acc[mi][ni] = __builtin_amdgcn_mfma_f32_16x16x32_bf16(a[mi], bfr[ni], acc[mi][ni], 0, 0, 0);
    }
    __syncthreads();
  }

  const float* bias_arr = (w == 0) ? bq : (w == 1) ? bk : (w == 2) ? bv : bg;
  float bnis[4];
#pragma unroll
  for (int ni = 0; ni < 4; ++ni) bnis[ni] = bias_arr[nloc0 + wn + ni * 16 + l15];
  const float qscale = 0.17677669529663687f * L2E;

#pragma unroll
  for (int mi = 0; mi < 4; ++mi)
#pragma unroll
    for (int ni = 0; ni < 4; ++ni)
#pragma unroll
      for (int r = 0; r < 4; ++r) {
        const int grow = m0 + wm + mi * 16 + l16 * 4 + r;
        const int gcol = nloc0 + wn + ni * 16 + l15;
        const float v = acc[mi][ni][r] + bnis[ni];
        const int n = grow >> 8, i2 = grow & 255, h = gcol >> 5, dh = gcol & 31;
        const size_t hoff = (((size_t)n * 8 + h) * 256 + i2) * 32 + dh;
        if (w == 0)      qb[hoff] = (__bf16)(v * qscale);
        else if (w == 1) kb[hoff] = (__bf16)v;
        else if (w == 2) vb[hoff] = (__bf16)v;
        else gateb[(size_t)grow * 256 + gcol] = (__bf16)(1.f / (1.f + __expf(-v)));
      }
}

// ---------------- flash attention: prefetch rotate, bias-as-C, permlane pack ----------------
__device__ __forceinline__ unsigned pk2(float a, float b) {
  bf16x2 t; t[0] = (__bf16)a; t[1] = (__bf16)b;
  return __builtin_bit_cast(unsigned, t);
}

__global__ __launch_bounds__(256) void attn_kernel(
    const __bf16* __restrict__ qb, const __bf16* __restrict__ kb,
    const __bf16* __restrict__ vb, const float* __restrict__ biasf,
    const int* __restrict__ mask, __bf16* __restrict__ opre)
{
  __shared__ alignas(16) __bf16 Vt[32 * VTS];   // V^T [dh][key]
  __shared__ alignas(16) float Ml[256];          // additive mask
  const int t = threadIdx.x, wave = t >> 6, lane = t & 63;
  const int l31 = lane & 31, hi = lane >> 5;
  const int bid = blockIdx.x, nh = bid >> 1, half = bid & 1;
  const int n = nh >> 3, h = nh & 7;
  const __bf16* kbh = kb + (size_t)nh * 8192;
  const __bf16* qbh = qb + (size_t)nh * 8192;

  { // stage V^T + mask (one-time)
    const bf16x8* vs = (const bf16x8*)(vb + (size_t)nh * 8192 + t * 32);
    bf16x8 vv[4];
#pragma unroll
    for (int j = 0; j < 4; ++j) vv[j] = vs[j];
#pragma unroll
    for (int j = 0; j < 4; ++j)
#pragma unroll
      for (int e = 0; e < 8; ++e) Vt[(j * 8 + e) * VTS + t] = vv[j][e];
    Ml[t] = mask[n * 256 + t] ? 0.f : -1e9f;
  }
  __syncthreads();

  const int q0 = half * 128 + wave * 32;
  const int q = q0 + l31;
  const bf16x8 Qf0 = *(const bf16x8*)(qbh + (size_t)q * 32 + hi * 8);
  const bf16x8 Qf1 = *(const bf16x8*)(qbh + (size_t)q * 32 + 16 + hi * 8);

  const float* bp = biasf + (size_t)h * 65536 + (size_t)q * 256;

  // prefetch tile 0
  bf16x8 Kc0 = *(const bf16x8*)(kbh + (size_t)l31 * 32 + hi * 8);
  bf16x8 Kc1 = *(const bf16x8*)(kbh + (size_t)l31 * 32 + 16 + hi * 8);
  f32x4 bc[4];
#pragma unroll
  for (int g = 0; g < 4; ++g) bc[g] = *(const f32x4*)(bp + 8 * g + 4 * hi);

  f32x16 Ot;
#pragma unroll
  for (int r = 0; r < 16; ++r) Ot[r] = 0.f;
  float lrun = 0.f;

#pragma unroll 1
  for (int kt = 0; kt < 8; ++kt) {
    const int k0 = kt * 32;
    const int ktn = (kt + 1) & 7;
    // st init = bias(f32) + mask (LDS broadcast)  [off critical path]
    f32x16 st;
#pragma unroll
    for (int g = 0; g < 4; ++g) {
      const f32x4 mk = *(const f32x4*)&Ml[k0 + 8 * g + 4 * hi];
#pragma unroll
      for (int e = 0; e < 4; ++e) st[4 * g + e] = bc[g][e] + mk[e];
    }
    st = __builtin_amdgcn_mfma_f32_32x32x16_bf16(Kc0, Qf0, st, 0, 0, 0);
    st = __builtin_amdgcn_mfma_f32_32x32x16_bf16(Kc1, Qf1, st, 0, 0, 0);
    // prefetch next tile (latency hidden under softmax+PV)
    Kc0 = *(const bf16x8*)(kbh + (size_t)(ktn * 32 + l31) * 32 + hi * 8);
    Kc1 = *(const bf16x8*)(kbh + (size_t)(ktn * 32 + l31) * 32 + 16 + hi * 8);
#pragma unroll
    for (int g = 0; g < 4; ++g)
      bc[g] = *(const f32x4*)(bp + ktn * 32 + 8 * g + 4 * hi);
    // softmax (no shift, log2 domain)
#pragma unroll
    for (int r = 0; r < 16; ++r) st[r] = exp2f(st[r]);
    float ts = st[0];
#pragma unroll
    for (int r = 1; r < 16; ++r) ts += st[r];
    SUM32(ts, lrun);
    // pack P -> bf16 B-fragments via permlane half-exchange (distinct operands)
    unsigned c0 = pk2(st[0],  st[1]),  c1 = pk2(st[2],  st[3]);
    unsigned c2 = pk2(st[4],  st[5]),  c3 = pk2(st[6],  st[7]);
    unsigned c4 = pk2(st[8],  st[9]),  c5 = pk2(st[10], st[11]);
    unsigned c6 = pk2(st[12], st[13]), c7 = pk2(st[14], st[15]);
    SWP(c0, c2); SWP(c1, c3); SWP(c4, c6); SWP(c5, c7);
    u32x4 w0 = {c0, c1, c2, c3}, w1 = {c4, c5, c6, c7};
    const bf16x8 pf0 = __builtin_bit_cast(bf16x8, w0);
    const bf16x8 pf1 = __builtin_bit_cast(bf16x8, w1);
    const bf16x8 Vf0 = *(const bf16x8*)&Vt[l31 * VTS + k0 + hi * 8];
    const bf16x8 Vf1 = *(const bf16x8*)&Vt[l31 * VTS + k0 + 16 + hi * 8];
    Ot = __builtin_amdgcn_mfma_f32_32x32x16_bf16(Vf0, pf0, Ot, 0, 0, 0);
    Ot = __builtin_amdgcn_mfma_f32_32x32x16_bf16(Vf1, pf1, Ot, 0, 0, 0);
  }

  // ---- epilogue: opre h-major [h][n][q][dh], permlane exchange, 2x16B stores ----
  const float invl = 1.f / lrun;
  unsigned P00 = pk2(Ot[0]  * invl, Ot[1]  * invl), P01 = pk2(Ot[2]  * invl, Ot[3]  * invl);
  unsigned P10 = pk2(Ot[4]  * invl, Ot[5]  * invl), P11 = pk2(Ot[6]  * invl, Ot[7]  * invl);
  unsigned P20 = pk2(Ot[8]  * invl, Ot[9]  * invl), P21 = pk2(Ot[10] * invl, Ot[11] * invl);
  unsigned P30 = pk2(Ot[12] * invl, Ot[13] * invl), P31 = pk2(Ot[14] * invl, Ot[15] * invl);
  SWP(P00, P20); SWP(P01, P21); SWP(P10, P30); SWP(P11, P31);
  u32x4 s0 = {P00, P01, P20, P21}, s1 = {P10, P11, P30, P31};
  __bf16* dst = opre + (((size_t)h * 128 + n) * 256 + q) * 32 + hi * 16;
  *(u32x4*)dst = s0;
  *(u32x4*)(dst + 8) = s1;
}

// ---------------- output projection + gate (unchanged) ----------------
__global__ __launch_bounds__(256) void wo_gemm(
    const __bf16* __restrict__ A, const __bf16* __restrict__ Wtw,
    const float* __restrict__ bo, const __bf16* __restrict__ gateb,
    float* __restrict__ out)
{
  __shared__ alignas(16) __bf16 Al[128 * 64];
  __shared__ alignas(16) __bf16 Bl[128 * 64];
  const int t = threadIdx.x;
  const int wave = t >> 6, lane = t & 63;
  const int l15 = lane & 15, l16 = lane >> 4;
  const int m0 = blockIdx.x * 128;
  const int nloc0 = blockIdx.y * 128;
  const int wm = (wave >> 1) * 64, wn = (wave & 1) * 64;

  const int srow = (lane >> 3);
  const int chunk = ((lane & 7) ^ srow) * 8;

  f32x4 acc[4][4];
#pragma unroll
  for (int i = 0; i < 4; ++i)
#pragma unroll
    for (int j = 0; j < 4; ++j) acc[i][j] = (f32x4){0.f, 0.f, 0.f, 0.f};

  for (int kt = 0; kt < 4; ++kt) {
    const int k0 = kt * 64;
#pragma unroll
    for (int i = 0; i < 4; ++i) {
      const int row = wave * 32 + i * 8 + srow;
      const int m = m0 + row;
      const int kg = k0 + chunk;
      GLOAD_LDS16(A + (size_t)(kg >> 5) * 1048576 + (size_t)(m >> 8) * 8192
                    + (m & 255) * 32 + (kg & 31),
                  &Al[(wave * 4 + i) * 512]);
      GLOAD_LDS16(Wtw + (size_t)(nloc0 + row) * 256 + kg, &Bl[(wave * 4 + i) * 512]);
    }
    __syncthreads();
#pragma unroll
    for (int kk = 0; kk < 2; ++kk) {
      bf16x8 a[4], bfr[4];
#pragma unroll
      for (int mi = 0; mi < 4; ++mi) {
        const int row = wm + mi * 16 + l15;
        a[mi] = *(const bf16x8*)&Al[row * 64 + ((kk * 32 + l16 * 8) ^ ((row & 7) << 3))];
      }
#pragma unroll
      for (int ni = 0; ni < 4; ++ni) {
        const int row = wn + ni * 16 + l15;
        bfr[ni] = *(const bf16x8*)&Bl[row * 64 + ((kk * 32 + l16 * 8) ^ ((row & 7) << 3))];
      }
#pragma unroll
      for (int mi = 0; mi < 4; ++mi)
#pragma unroll
        for (int ni = 0; ni < 4; ++ni)
          acc[mi][ni] = __builtin_amdgcn_mfma_f32_16x16x32_bf16(a[mi], bfr[ni], acc[mi][ni], 0, 0, 0);
    }
    __syncthreads();
  }

  float bov[4];
#pragma unroll
  for (int ni = 0; ni < 4; ++ni) bov[ni] = bo[nloc0 + wn + ni * 16 + l15];
#pragma unroll
  for (int mi = 0; mi < 4; ++mi)
#pragma unroll
    for (int ni = 0; ni < 4; ++ni)
#pragma unroll
      for (int r = 0; r < 4; ++r) {
        const int grow = m0 + wm + mi * 16 + l16 * 4 + r;
        const int gcol = nloc0 + wn + ni * 16 + l15;
        const size_t o = (size_t)grow * 256 + gcol;
        out[o] = (acc[mi][ni][r] + bov[ni]) * (float)gateb[o];
      }
}

extern "C" void kernel_launch(void* const* d_in, const int* in_sizes, int n_in,
                              void* d_out, int out_size, void* d_ws, size_t ws_size,
                              hipStream_t stream)
{
  const float* msa  = (const float*)d_in[0];
  const float* pair = (const float*)d_in[1];
  const int*   mask = (const int*)d_in[2];
  const float* ln_g = (const float*)d_in[3];
  const float* ln_b = (const float*)d_in[4];
  const float* Wq = (const float*)d_in[5];  const float* bq = (const float*)d_in[6];
  const float* Wk = (const float*)d_in[7];  const float* bk = (const float*)d_in[8];
  const float* Wv = (const float*)d_in[9];  const float* bv = (const float*)d_in[10];
  const float* Wb = (const float*)d_in[11]; const float* bb = (const float*)d_in[12];
  const float* Wo = (const float*)d_in[13]; const float* bo = (const float*)d_in[14];
  const float* Wg = (const float*)d_in[15]; const float* bg = (const float*)d_in[16];
  float* out = (float*)d_out;

  char* ws = (char*)d_ws;
  __bf16* xn    = (__bf16*)(ws);
  __bf16* qb    = (__bf16*)(ws + 16777216);
  __bf16* kb    = (__bf16*)(ws + 2 * 16777216);
  __bf16* vb    = (__bf16*)(ws + 3 * 16777216);
  __bf16* opre  = (__bf16*)(ws + 4 * 16777216);
  __bf16* Wt    = (__bf16*)(ws + 5 * 16777216);                      // 640KB
  __bf16* gateb = (__bf16*)(ws + 5 * 16777216 + 655360);             // 16.8MB
  float*  biasf = (float*)(ws + 5 * 16777216 + 655360 + 16777216);   // 2MB [h][q][k]

  hipLaunchKernelGGL(ln_kernel,   dim3(8192),   dim3(256), 0, stream, msa, ln_g, ln_b, xn);
  hipLaunchKernelGGL(bias_kernel, dim3(256),    dim3(256), 0, stream, pair, Wb, bb, biasf);
  hipLaunchKernelGGL(prep_kernel, dim3(1280),   dim3(256), 0, stream, Wq, Wk, Wv, Wg, Wo, Wt);
  hipLaunchKernelGGL(qkvg_gemm,   dim3(256, 8), dim3(256), 0, stream, xn, Wt, bq, bk, bv, bg, qb, kb, vb, gateb);
  hipLaunchKernelGGL(attn_kernel, dim3(2048),   dim3(256), 0, stream, qb, kb, vb, biasf, mask, opre);
  hipLaunchKernelGGL(wo_gemm,     dim3(256, 2), dim3(256), 0, stream, opre, Wt + 4 * 65536, bo, gateb, out);
}